// Round 1
// baseline (9914.133 us; speedup 1.0000x reference)
//
#include <hip/hip_runtime.h>
#include <cstdint>

// ---------------- geometry ----------------
constexpr int BB = 2;           // batch
constexpr int C  = 64;          // channels
constexpr int D1 = 31;          // conv1 out / conv2,3 spatial
constexpr int DP = 33;          // padded spatial for x1..x3 (and raw input grid)
constexpr int D4 = 63;          // conv_transpose out spatial
constexpr int D5 = 61;          // conv5 out spatial

constexpr int NV1 = BB*D1*D1*D1;   // 59582
constexpr int NVP = BB*DP*DP*DP;   // 71874
constexpr int NV4 = BB*D4*D4*D4;   // 500094
constexpr int NV5 = BB*D5*D5*D5;   // 453962

// ---------------- workspace layout (float offsets) ----------------
constexpr long long OFF_X0 = 0;                              // [NVP][3] raw scatter grid
constexpr long long OFF_M0 = OFF_X0 + (long long)NVP*3;      // [NVP] mask
constexpr long long OFF_X1 = OFF_M0 + NVP;                   // [B][33][33][33][64] padded
constexpr long long OFF_M1 = OFF_X1 + (long long)NVP*C;      // [NV1] mask (f32 0/1)
constexpr long long OFF_X2 = OFF_M1 + 59584;                 // padded
constexpr long long OFF_X3 = OFF_X2 + (long long)NVP*C;      // padded
constexpr long long OFF_X4 = OFF_X3 + (long long)NVP*C;      // [B][63][63][63][64]
constexpr long long WS_END = OFF_X4 + (long long)NV4*C;      // ~184.6 MB

// ---------------- kernels ----------------
__global__ void k_scatter(const float* __restrict__ feat, const int* __restrict__ coors,
                          int n, float* __restrict__ ws) {
  int i = blockIdx.x*blockDim.x + threadIdx.x;
  if (i >= n) return;
  int b = coors[4*i+0], z = coors[4*i+1], y = coors[4*i+2], x = coors[4*i+3];
  int v = ((b*DP + z)*DP + y)*DP + x;
  float* x0 = ws + OFF_X0;
  x0[v*3+0] = feat[3*i+0];
  x0[v*3+1] = feat[3*i+1];
  x0[v*3+2] = feat[3*i+2];
  ws[OFF_M0 + v] = 1.0f;
}

// conv1: 3 -> 64, VALID, + m1 mask + act.  one thread per (vox,co)
__global__ void __launch_bounds__(256)
k_conv1(float* __restrict__ ws, const float* __restrict__ w1, const float* __restrict__ b1,
        const float* __restrict__ s1, const float* __restrict__ h1) {
  long long t = (long long)blockIdx.x*blockDim.x + threadIdx.x;
  if (t >= (long long)NV1*C) return;
  int co  = (int)(t & 63);
  int vox = (int)(t >> 6);
  int x = vox % D1; int r = vox / D1;
  int y = r % D1;   r /= D1;
  int z = r % D1;   int b = r / D1;
  const float* x0 = ws + OFF_X0;
  const float* m0 = ws + OFF_M0;
  float sum = 0.f, mm = 0.f;
  #pragma unroll
  for (int kz=0; kz<3; kz++)
  #pragma unroll
  for (int ky=0; ky<3; ky++)
  #pragma unroll
  for (int kx=0; kx<3; kx++) {
    int iv = ((b*DP + z+kz)*DP + y+ky)*DP + (x+kx);
    mm += m0[iv];
    const float* px = x0 + iv*3;
    const float* pw = w1 + ((kz*3+ky)*3+kx)*3*64 + co;
    sum += px[0]*pw[0] + px[1]*pw[64] + px[2]*pw[128];
  }
  bool m = mm > 0.f;
  float o = m ? fmaxf((sum + b1[co])*s1[co] + h1[co], 0.f) : 0.f;
  // padded write at (z+1, y+1, x+1)
  ws[OFF_X1 + (long long)(((b*DP + z+1)*DP + y+1)*DP + (x+1))*C + co] = o;
  if (co == 0) ws[OFF_M1 + vox] = m ? 1.f : 0.f;
}

// conv 64->64 SAME over 31^3 using padded 33^3 input; wave = 64 co x 8 voxels
__global__ void __launch_bounds__(256)
k_conv_same(const float* __restrict__ in, float* __restrict__ out,
            const float* __restrict__ m1, const float* __restrict__ w,
            const float* __restrict__ bias, const float* __restrict__ s,
            const float* __restrict__ h) {
  int wave = blockIdx.x*4 + (threadIdx.x>>6);
  int co = threadIdx.x & 63;
  int vb = wave*8;
  int zz[8], yy[8], xx[8], bb[8];
  #pragma unroll
  for (int v=0; v<8; v++) {
    int vox = min(vb+v, NV1-1);
    int x = vox % D1; int r = vox / D1;
    int y = r % D1;   r /= D1;
    zz[v] = r % D1;   bb[v] = r / D1;
    yy[v] = y; xx[v] = x;
  }
  float acc[8] = {0,0,0,0,0,0,0,0};
  #pragma unroll 1
  for (int t=0; t<27; t++) {
    int kx = t%3, r2 = t/3; int ky = r2%3, kz = r2/3;
    int offs[8];
    #pragma unroll
    for (int v=0; v<8; v++)
      offs[v] = (((bb[v]*DP + zz[v]+kz)*DP + yy[v]+ky)*DP + (xx[v]+kx))*C;
    const float* wt = w + t*4096 + co;
    #pragma unroll 2
    for (int ci=0; ci<64; ci+=4) {
      float w0 = wt[(ci+0)*64], w1v = wt[(ci+1)*64];
      float w2v = wt[(ci+2)*64], w3v = wt[(ci+3)*64];
      #pragma unroll
      for (int v=0; v<8; v++) {
        const float4 iv = *reinterpret_cast<const float4*>(in + offs[v] + ci);
        acc[v] = fmaf(iv.x, w0, acc[v]);
        acc[v] = fmaf(iv.y, w1v, acc[v]);
        acc[v] = fmaf(iv.z, w2v, acc[v]);
        acc[v] = fmaf(iv.w, w3v, acc[v]);
      }
    }
  }
  float bv = bias[co], sv = s[co], hv = h[co];
  #pragma unroll
  for (int v=0; v<8; v++) {
    int vox = vb+v;
    if (vox >= NV1) break;
    float o = (m1[vox] > 0.f) ? fmaxf((acc[v]+bv)*sv+hv, 0.f) : 0.f;
    out[(long long)(((bb[v]*DP + zz[v]+1)*DP + yy[v]+1)*DP + (xx[v]+1))*C + co] = o;
  }
}

// conv_transpose stride2 VALID 64->64: 31^3 -> 63^3, + mT + act
__global__ void __launch_bounds__(256)
k_convT(const float* __restrict__ in /*x3 padded*/, float* __restrict__ out /*x4*/,
        const float* __restrict__ m1, const float* __restrict__ w,
        const float* __restrict__ bias, const float* __restrict__ s,
        const float* __restrict__ h) {
  int wave = blockIdx.x*4 + (threadIdx.x>>6);
  int co = threadIdx.x & 63;
  int vb = wave*8;
  float bv = bias[co], sv = s[co], hv = h[co];
  #pragma unroll 1
  for (int v=0; v<8; v++) {
    int vox = vb+v;
    if (vox >= NV4) return;                  // uniform across wave
    int xo = vox % D4; int r = vox / D4;
    int yo = r % D4;   r /= D4;
    int zo = r % D4;   int b = r / D4;
    float acc = 0.f, mm = 0.f;
    for (int kz=0; kz<3; kz++) {
      int pz = zo + kz - 2;
      if (pz < 0 || (pz & 1) || (pz>>1) >= D1) continue;
      int iz = pz >> 1;
      for (int ky=0; ky<3; ky++) {
        int py = yo + ky - 2;
        if (py < 0 || (py & 1) || (py>>1) >= D1) continue;
        int iy = py >> 1;
        for (int kx=0; kx<3; kx++) {
          int px = xo + kx - 2;
          if (px < 0 || (px & 1) || (px>>1) >= D1) continue;
          int ix = px >> 1;
          mm += m1[((b*D1 + iz)*D1 + iy)*D1 + ix];
          const float* bp = in + (((b*DP + iz+1)*DP + iy+1)*DP + (ix+1))*C;
          const float* wt = w + ((kz*3+ky)*3+kx)*4096 + co;
          #pragma unroll 4
          for (int ci=0; ci<64; ci+=4) {
            const float4 iv = *reinterpret_cast<const float4*>(bp + ci);
            acc = fmaf(iv.x, wt[(ci+0)*64], acc);
            acc = fmaf(iv.y, wt[(ci+1)*64], acc);
            acc = fmaf(iv.z, wt[(ci+2)*64], acc);
            acc = fmaf(iv.w, wt[(ci+3)*64], acc);
          }
        }
      }
    }
    float o = (mm > 0.f) ? fmaxf((acc+bv)*sv+hv, 0.f) : 0.f;
    out[(long long)vox*C + co] = o;
  }
}

// conv5: 64->64 VALID over 63^3 -> 61^3, final relu(x*s+h), transposed NCDHW store
__global__ void __launch_bounds__(256)
k_conv5(const float* __restrict__ in /*x4*/, float* __restrict__ out /*d_out*/,
        const float* __restrict__ w, const float* __restrict__ bias,
        const float* __restrict__ s, const float* __restrict__ h) {
  int wave = blockIdx.x*4 + (threadIdx.x>>6);
  int co = threadIdx.x & 63;
  int vb = wave*8;
  int zz[8], yy[8], xx[8], bb[8];
  #pragma unroll
  for (int v=0; v<8; v++) {
    int vox = min(vb+v, NV5-1);
    int x = vox % D5; int r = vox / D5;
    int y = r % D5;   r /= D5;
    zz[v] = r % D5;   bb[v] = r / D5;
    yy[v] = y; xx[v] = x;
  }
  float acc[8] = {0,0,0,0,0,0,0,0};
  #pragma unroll 1
  for (int t=0; t<27; t++) {
    int kx = t%3, r2 = t/3; int ky = r2%3, kz = r2/3;
    int offs[8];
    #pragma unroll
    for (int v=0; v<8; v++)
      offs[v] = (((bb[v]*D4 + zz[v]+kz)*D4 + yy[v]+ky)*D4 + (xx[v]+kx))*C;
    const float* wt = w + t*4096 + co;
    #pragma unroll 2
    for (int ci=0; ci<64; ci+=4) {
      float w0 = wt[(ci+0)*64], w1v = wt[(ci+1)*64];
      float w2v = wt[(ci+2)*64], w3v = wt[(ci+3)*64];
      #pragma unroll
      for (int v=0; v<8; v++) {
        const float4 iv = *reinterpret_cast<const float4*>(in + offs[v] + ci);
        acc[v] = fmaf(iv.x, w0, acc[v]);
        acc[v] = fmaf(iv.y, w1v, acc[v]);
        acc[v] = fmaf(iv.z, w2v, acc[v]);
        acc[v] = fmaf(iv.w, w3v, acc[v]);
      }
    }
  }
  float bv = bias[co], sv = s[co], hv = h[co];
  #pragma unroll
  for (int v=0; v<8; v++) {
    int vox = vb+v;
    if (vox >= NV5) break;
    float o = fmaxf((acc[v]+bv)*sv+hv, 0.f);
    out[(long long)(((bb[v]*C + co)*D5 + zz[v])*D5 + yy[v])*D5 + xx[v]] = o;
  }
}

// ---------------- launcher ----------------
extern "C" void kernel_launch(void* const* d_in, const int* in_sizes, int n_in,
                              void* d_out, int out_size, void* d_ws, size_t ws_size,
                              hipStream_t stream) {
  const float* feat = (const float*)d_in[0];
  const int*   coors = (const int*)d_in[1];
  const float* w1 = (const float*)d_in[3];
  const float* b1 = (const float*)d_in[4];
  const float* w2 = (const float*)d_in[5];
  const float* b2 = (const float*)d_in[6];
  const float* w3 = (const float*)d_in[7];
  const float* b3 = (const float*)d_in[8];
  const float* wt = (const float*)d_in[9];
  const float* bt = (const float*)d_in[10];
  const float* w5 = (const float*)d_in[11];
  const float* b5 = (const float*)d_in[12];
  const float* s1 = (const float*)d_in[13];
  const float* h1 = (const float*)d_in[14];
  const float* s2 = (const float*)d_in[15];
  const float* h2 = (const float*)d_in[16];
  const float* s3 = (const float*)d_in[17];
  const float* h3 = (const float*)d_in[18];
  const float* s4 = (const float*)d_in[19];
  const float* h4 = (const float*)d_in[20];
  const float* s5 = (const float*)d_in[21];
  const float* h5 = (const float*)d_in[22];
  int n = in_sizes[0] / 3;
  float* ws = (float*)d_ws;

  // zero scatter grid + masks + padded x1..x3 borders (x4 and d_out fully overwritten)
  hipMemsetAsync(ws, 0, (size_t)OFF_X4 * sizeof(float), stream);

  k_scatter<<<(n+255)/256, 256, 0, stream>>>(feat, coors, n, ws);

  {
    long long threads = (long long)NV1*C;
    k_conv1<<<(int)((threads+255)/256), 256, 0, stream>>>(ws, w1, b1, s1, h1);
  }
  int waves1 = (NV1+7)/8;
  k_conv_same<<<(waves1+3)/4, 256, 0, stream>>>(ws+OFF_X1, ws+OFF_X2, ws+OFF_M1, w2, b2, s2, h2);
  k_conv_same<<<(waves1+3)/4, 256, 0, stream>>>(ws+OFF_X2, ws+OFF_X3, ws+OFF_M1, w3, b3, s3, h3);

  int waves4 = (NV4+7)/8;
  k_convT<<<(waves4+3)/4, 256, 0, stream>>>(ws+OFF_X3, ws+OFF_X4, ws+OFF_M1, wt, bt, s4, h4);

  int waves5 = (NV5+7)/8;
  k_conv5<<<(waves5+3)/4, 256, 0, stream>>>(ws+OFF_X4, (float*)d_out, w5, b5, s5, h5);
}

// Round 2
// 1903.875 us; speedup vs baseline: 5.2073x; 5.2073x over previous
//
#include <hip/hip_runtime.h>
#include <cstdint>

// ---------------- geometry ----------------
constexpr int BB = 2, C = 64;
constexpr int D1 = 31;          // conv1 out / conv2,3 spatial
constexpr int DP = 33;          // padded spatial for x1..x3
constexpr int D4 = 63;          // conv_transpose out spatial
constexpr int D5 = 61;          // conv5 out spatial
constexpr int D5CUBE = D5*D5*D5;          // 226981

constexpr int NV1 = BB*D1*D1*D1;   // 59582
constexpr int NVP = BB*DP*DP*DP;   // 71874
constexpr int NV4 = BB*D4*D4*D4;   // 500094
constexpr int NV5 = BB*D5*D5*D5;   // 453962

// ---------------- workspace layout (byte offsets) ----------------
constexpr size_t OB_X0  = 0;                                   // [NVP][3] f32
constexpr size_t OB_M0  = OB_X0 + (size_t)NVP*3*4;             // [NVP] f32
constexpr size_t OB_M1  = OB_M0 + (size_t)NVP*4;               // [NV1] f32
constexpr size_t OB_X1  = 1388544;                             // [NVP][64] bf16 (padded)
constexpr size_t OB_X2  = OB_X1 + (size_t)NVP*64*2;            // [NVP][64] bf16 (padded)
constexpr size_t OB_X3  = OB_X2 + (size_t)NVP*64*2;            // [NVP][64] f32 (padded)
constexpr size_t OB_X4  = OB_X3 + (size_t)NVP*64*4;            // [NV4][64] bf16
constexpr size_t OB_WB2 = OB_X4 + (size_t)NV4*64*2;            // repacked weights bf16
constexpr size_t OB_WB3 = OB_WB2 + (size_t)27*64*64*2;
constexpr size_t OB_WB5 = OB_WB3 + (size_t)27*64*64*2;

// ---------------- types / helpers ----------------
typedef __attribute__((ext_vector_type(8))) short short8;
typedef __attribute__((ext_vector_type(4))) float f32x4;

__device__ inline unsigned short f2bf(float f) {
  unsigned int u = __float_as_uint(f);
  u = (u + 0x7FFFu + ((u >> 16) & 1u)) >> 16;   // round-to-nearest-even
  return (unsigned short)u;
}
__device__ inline float bf2f(unsigned short s) {
  return __uint_as_float(((unsigned int)s) << 16);
}

template<int DD>
__device__ inline void decodev(int vox, int& b, int& z, int& y, int& x) {
  x = vox % DD; int r = vox / DD;
  y = r % DD;   r /= DD;
  z = r % DD;   b = r / DD;
}

// ---------------- scatter ----------------
__global__ void k_scatter(const float* __restrict__ feat, const int* __restrict__ coors,
                          int n, float* __restrict__ x0, float* __restrict__ m0) {
  int i = blockIdx.x*blockDim.x + threadIdx.x;
  if (i >= n) return;
  int b = coors[4*i+0], z = coors[4*i+1], y = coors[4*i+2], x = coors[4*i+3];
  int v = ((b*DP + z)*DP + y)*DP + x;
  x0[v*3+0] = feat[3*i+0];
  x0[v*3+1] = feat[3*i+1];
  x0[v*3+2] = feat[3*i+2];
  m0[v] = 1.0f;
}

// ---------------- conv1: 3 -> 64, VALID, mask+act, bf16 out ----------------
__global__ void __launch_bounds__(256)
k_conv1(const float* __restrict__ x0, const float* __restrict__ m0,
        unsigned short* __restrict__ x1, float* __restrict__ m1out,
        const float* __restrict__ w1, const float* __restrict__ b1,
        const float* __restrict__ s1, const float* __restrict__ h1) {
  long long t = (long long)blockIdx.x*blockDim.x + threadIdx.x;
  if (t >= (long long)NV1*C) return;
  int co  = (int)(t & 63);
  int vox = (int)(t >> 6);
  int b, z, y, x; decodev<D1>(vox, b, z, y, x);
  float sum = 0.f, mm = 0.f;
  #pragma unroll
  for (int kz=0; kz<3; kz++)
  #pragma unroll
  for (int ky=0; ky<3; ky++)
  #pragma unroll
  for (int kx=0; kx<3; kx++) {
    int iv = ((b*DP + z+kz)*DP + y+ky)*DP + (x+kx);
    mm += m0[iv];
    const float* px = x0 + iv*3;
    const float* pw = w1 + ((kz*3+ky)*3+kx)*3*64 + co;
    sum += px[0]*pw[0] + px[1]*pw[64] + px[2]*pw[128];
  }
  bool m = mm > 0.f;
  float o = m ? fmaxf((sum + b1[co])*s1[co] + h1[co], 0.f) : 0.f;
  x1[(size_t)(((b*DP + z+1)*DP + y+1)*DP + (x+1))*C + co] = f2bf(o);
  if (co == 0) m1out[vox] = m ? 1.f : 0.f;
}

// ---------------- weight repack into B-fragment lane order ----------------
// wB[((t*2+kk)*4+cb)*512 + l*8 + j] = bf16(w[t][k][co]),
//   k = kk*32 + (l>>4)*8 + j, co = cb*16 + (l&15)
__global__ void k_repack(const float* __restrict__ w, unsigned short* __restrict__ dst) {
  int i = blockIdx.x*256 + threadIdx.x;
  if (i >= 27*64*64) return;
  int co = i & 63, k = (i >> 6) & 63, t = i >> 12;
  int kk = k >> 5, q = (k >> 3) & 3, j = k & 7, cb = co >> 4, l = q*16 + (co & 15);
  dst[(size_t)((t*2+kk)*4+cb)*512 + l*8 + j] = f2bf(w[i]);
}

// ---------------- MFMA implicit-GEMM conv (3^3, 64->64) ----------------
// OUTMODE: 0 = padded bf16 + mask/act, 1 = padded f32 + mask/act,
//          2 = NCDHW f32 (d_out) + act, LDS-transposed stores
template<int NA, int DOUT, int DIN, int OUTMODE>
__global__ void __launch_bounds__(256)
k_conv_mfma(const unsigned short* __restrict__ inBF, const unsigned short* __restrict__ wB,
            void* __restrict__ outPtr, const float* __restrict__ m1,
            const float* __restrict__ bias, const float* __restrict__ s,
            const float* __restrict__ h) {
  constexpr int NVOX = BB*DOUT*DOUT*DOUT;
  const int lane = threadIdx.x & 63;
  const int wid  = threadIdx.x >> 6;
  const int wave = blockIdx.x*4 + wid;
  const int vb   = wave * (NA*16);

  // per-lane A-row base offsets (elements) in the input grid
  int rowb[NA];
  #pragma unroll
  for (int a = 0; a < NA; a++) {
    int vox = vb + a*16 + (lane & 15);
    vox = vox < NVOX ? vox : NVOX-1;
    int b, z, y, x; decodev<DOUT>(vox, b, z, y, x);
    rowb[a] = (((b*DIN + z)*DIN + y)*DIN + x)*64;
  }
  const int koff = (lane >> 4) * 8;

  f32x4 acc[NA][4];
  #pragma unroll
  for (int a = 0; a < NA; a++)
    #pragma unroll
    for (int cb = 0; cb < 4; cb++)
      acc[a][cb] = f32x4{0.f, 0.f, 0.f, 0.f};

  #pragma unroll 1
  for (int t = 0; t < 27; ++t) {
    int kz = t / 9, rr = t - kz*9;
    int ky = rr / 3, kx = rr - ky*3;
    const int toff = ((kz*DIN + ky)*DIN + kx)*64;
    #pragma unroll
    for (int kk = 0; kk < 2; ++kk) {
      short8 A[NA];
      #pragma unroll
      for (int a = 0; a < NA; a++)
        A[a] = *reinterpret_cast<const short8*>(inBF + rowb[a] + toff + kk*32 + koff);
      short8 Bv[4];
      const unsigned short* wp = wB + (size_t)(t*2+kk)*2048 + lane*8;
      #pragma unroll
      for (int cb = 0; cb < 4; cb++)
        Bv[cb] = *reinterpret_cast<const short8*>(wp + cb*512);
      #pragma unroll
      for (int a = 0; a < NA; a++)
        #pragma unroll
        for (int cb = 0; cb < 4; cb++)
          acc[a][cb] = __builtin_amdgcn_mfma_f32_16x16x32_bf16(A[a], Bv[cb], acc[a][cb], 0, 0, 0);
    }
  }

  // epilogue params (co = cb*16 + (lane&15))
  float bv[4], sv[4], hv[4];
  #pragma unroll
  for (int cb = 0; cb < 4; cb++) {
    int c = cb*16 + (lane & 15);
    bv[cb] = bias[c]; sv[cb] = s[c]; hv[cb] = h[c];
  }

  if constexpr (OUTMODE == 2) {
    __shared__ float lds[4][32*65];
    float* L = lds[wid];
    float* out = (float*)outPtr;
    #pragma unroll
    for (int hh = 0; hh < 2; ++hh) {
      #pragma unroll
      for (int a2 = 0; a2 < 2; a2++) {
        int a = 2*hh + a2;
        #pragma unroll
        for (int cb = 0; cb < 4; cb++)
          #pragma unroll
          for (int r = 0; r < 4; r++) {
            float o = fmaxf((acc[a][cb][r] + bv[cb])*sv[cb] + hv[cb], 0.f);
            L[(a2*16 + (lane>>4)*4 + r)*65 + cb*16 + (lane & 15)] = o;
          }
      }
      __syncthreads();
      #pragma unroll 4
      for (int cc = 0; cc < 32; ++cc) {
        int co  = 2*cc + (lane >> 5);
        int vox = vb + hh*32 + (lane & 31);
        if (vox < NVOX) {
          float v = L[(lane & 31)*65 + co];
          int b = vox >= D5CUBE ? 1 : 0;
          out[(size_t)(b*64 + co)*D5CUBE + (vox - b*D5CUBE)] = v;
        }
      }
      __syncthreads();
    }
  } else {
    #pragma unroll
    for (int a = 0; a < NA; a++)
      #pragma unroll
      for (int r = 0; r < 4; r++) {
        int vox = vb + a*16 + (lane >> 4)*4 + r;
        if (vox >= NVOX) continue;
        bool m = m1[vox] > 0.f;
        int b, z, y, x; decodev<DOUT>(vox, b, z, y, x);
        size_t oOff = (size_t)(((b*DP + z+1)*DP + y+1)*DP + (x+1))*64;
        #pragma unroll
        for (int cb = 0; cb < 4; cb++) {
          float o = m ? fmaxf((acc[a][cb][r] + bv[cb])*sv[cb] + hv[cb], 0.f) : 0.f;
          if constexpr (OUTMODE == 0)
            ((unsigned short*)outPtr)[oOff + cb*16 + (lane & 15)] = f2bf(o);
          else
            ((float*)outPtr)[oOff + cb*16 + (lane & 15)] = o;
        }
      }
  }
}

// ---------------- conv_transpose stride2 VALID (vector f32, bf16 out) ----------------
__global__ void __launch_bounds__(256)
k_convT(const float* __restrict__ in /*x3 padded f32*/, unsigned short* __restrict__ out /*x4 bf16*/,
        const float* __restrict__ m1, const float* __restrict__ w,
        const float* __restrict__ bias, const float* __restrict__ s,
        const float* __restrict__ h) {
  int wave = blockIdx.x*4 + (threadIdx.x >> 6);
  int co = threadIdx.x & 63;
  int vb = wave*8;
  float bv = bias[co], sv = s[co], hv = h[co];
  #pragma unroll 1
  for (int v = 0; v < 8; v++) {
    int vox = vb + v;
    if (vox >= NV4) return;
    int xo = vox % D4; int r = vox / D4;
    int yo = r % D4;   r /= D4;
    int zo = r % D4;   int b = r / D4;
    float acc = 0.f, mm = 0.f;
    for (int kz = 0; kz < 3; kz++) {
      int pz = zo + kz - 2;
      if (pz < 0 || (pz & 1) || (pz >> 1) >= D1) continue;
      int iz = pz >> 1;
      for (int ky = 0; ky < 3; ky++) {
        int py = yo + ky - 2;
        if (py < 0 || (py & 1) || (py >> 1) >= D1) continue;
        int iy = py >> 1;
        for (int kx = 0; kx < 3; kx++) {
          int px = xo + kx - 2;
          if (px < 0 || (px & 1) || (px >> 1) >= D1) continue;
          int ix = px >> 1;
          mm += m1[((b*D1 + iz)*D1 + iy)*D1 + ix];
          const float* bp = in + (size_t)(((b*DP + iz+1)*DP + iy+1)*DP + (ix+1))*C;
          const float* wt = w + ((kz*3+ky)*3+kx)*4096 + co;
          #pragma unroll 4
          for (int ci = 0; ci < 64; ci += 4) {
            const float4 iv = *reinterpret_cast<const float4*>(bp + ci);
            acc = fmaf(iv.x, wt[(ci+0)*64], acc);
            acc = fmaf(iv.y, wt[(ci+1)*64], acc);
            acc = fmaf(iv.z, wt[(ci+2)*64], acc);
            acc = fmaf(iv.w, wt[(ci+3)*64], acc);
          }
        }
      }
    }
    float o = (mm > 0.f) ? fmaxf((acc + bv)*sv + hv, 0.f) : 0.f;
    out[(size_t)vox*C + co] = f2bf(o);
  }
}

// ---------------- launcher ----------------
extern "C" void kernel_launch(void* const* d_in, const int* in_sizes, int n_in,
                              void* d_out, int out_size, void* d_ws, size_t ws_size,
                              hipStream_t stream) {
  const float* feat  = (const float*)d_in[0];
  const int*   coors = (const int*)d_in[1];
  const float* w1 = (const float*)d_in[3];
  const float* b1 = (const float*)d_in[4];
  const float* w2 = (const float*)d_in[5];
  const float* b2 = (const float*)d_in[6];
  const float* w3 = (const float*)d_in[7];
  const float* b3 = (const float*)d_in[8];
  const float* wt = (const float*)d_in[9];
  const float* bt = (const float*)d_in[10];
  const float* w5 = (const float*)d_in[11];
  const float* b5 = (const float*)d_in[12];
  const float* s1 = (const float*)d_in[13];
  const float* h1 = (const float*)d_in[14];
  const float* s2 = (const float*)d_in[15];
  const float* h2 = (const float*)d_in[16];
  const float* s3 = (const float*)d_in[17];
  const float* h3 = (const float*)d_in[18];
  const float* s4 = (const float*)d_in[19];
  const float* h4 = (const float*)d_in[20];
  const float* s5 = (const float*)d_in[21];
  const float* h5 = (const float*)d_in[22];
  int n = in_sizes[0] / 3;

  char* wsb = (char*)d_ws;
  float*          X0  = (float*)(wsb + OB_X0);
  float*          M0  = (float*)(wsb + OB_M0);
  float*          M1  = (float*)(wsb + OB_M1);
  unsigned short* X1  = (unsigned short*)(wsb + OB_X1);
  unsigned short* X2  = (unsigned short*)(wsb + OB_X2);
  float*          X3  = (float*)(wsb + OB_X3);
  unsigned short* X4  = (unsigned short*)(wsb + OB_X4);
  unsigned short* WB2 = (unsigned short*)(wsb + OB_WB2);
  unsigned short* WB3 = (unsigned short*)(wsb + OB_WB3);
  unsigned short* WB5 = (unsigned short*)(wsb + OB_WB5);

  // zero x0/m0/m1 and padded x1/x2 (x3 centers fully rewritten & only centers read;
  // x4/d_out fully rewritten)
  hipMemsetAsync(wsb, 0, OB_X3, stream);

  k_repack<<<432, 256, 0, stream>>>(w2, WB2);
  k_repack<<<432, 256, 0, stream>>>(w3, WB3);
  k_repack<<<432, 256, 0, stream>>>(w5, WB5);

  k_scatter<<<(n+255)/256, 256, 0, stream>>>(feat, coors, n, X0, M0);

  {
    long long threads = (long long)NV1*C;
    k_conv1<<<(int)((threads+255)/256), 256, 0, stream>>>(X0, M0, X1, M1, w1, b1, s1, h1);
  }

  // conv2, conv3: 32 voxels/wave
  constexpr int WAVES23 = (NV1 + 31) / 32;
  constexpr int BLK23   = (WAVES23 + 3) / 4;
  k_conv_mfma<2, D1, DP, 0><<<BLK23, 256, 0, stream>>>(X1, WB2, X2, M1, b2, s2, h2);
  k_conv_mfma<2, D1, DP, 1><<<BLK23, 256, 0, stream>>>(X2, WB3, X3, M1, b3, s3, h3);

  int waves4 = (NV4 + 7) / 8;
  k_convT<<<(waves4+3)/4, 256, 0, stream>>>(X3, X4, M1, wt, bt, s4, h4);

  // conv5: 64 voxels/wave
  constexpr int WAVES5 = (NV5 + 63) / 64;
  constexpr int BLK5   = (WAVES5 + 3) / 4;
  k_conv_mfma<4, D5, D4, 2><<<BLK5, 256, 0, stream>>>(X4, WB5, d_out, nullptr, b5, s5, h5);
}

// Round 3
// 525.184 us; speedup vs baseline: 18.8774x; 3.6252x over previous
//
#include <hip/hip_runtime.h>
#include <cstdint>

// ---------------- geometry ----------------
constexpr int BB = 2, C = 64;
constexpr int D1 = 31;          // conv1 out / conv2,3 spatial
constexpr int DP = 33;          // padded spatial for x1..x3
constexpr int D4 = 63;          // conv_transpose out spatial
constexpr int D5 = 61;          // conv5 out spatial
constexpr int D5CUBE = D5*D5*D5;   // 226981

constexpr int NV1 = BB*D1*D1*D1;   // 59582
constexpr int NVP = BB*DP*DP*DP;   // 71874
constexpr int NV4 = BB*D4*D4*D4;   // 500094
constexpr int NV5 = BB*D5*D5*D5;   // 453962

// ---------------- workspace layout (byte offsets) ----------------
constexpr size_t alup(size_t x) { return (x + 255) & ~(size_t)255; }
constexpr size_t OB_X0  = 0;                                     // [NVP][3] f32
constexpr size_t OB_M0  = alup(OB_X0  + (size_t)NVP*3*4);        // [NVP] f32
constexpr size_t OB_M1P = alup(OB_M0  + (size_t)NVP*4);          // [NVP] f32 padded mask
constexpr size_t OB_X1  = alup(OB_M1P + (size_t)NVP*4);          // [NVP][64] bf16 padded
constexpr size_t OB_X2  = alup(OB_X1  + (size_t)NVP*64*2);       // [NVP][64] bf16 padded
constexpr size_t OB_X3  = alup(OB_X2  + (size_t)NVP*64*2);       // [NVP][64] bf16 padded
constexpr size_t OB_MT  = alup(OB_X3  + (size_t)NVP*64*2);       // [NV4] f32 (fully rewritten)
constexpr size_t OB_X4  = alup(OB_MT  + (size_t)NV4*4);          // [NV4][64] bf16 (fully rewritten)
constexpr size_t OB_WB2 = alup(OB_X4  + (size_t)NV4*64*2);
constexpr size_t OB_WB3 = alup(OB_WB2 + (size_t)27*64*64*2);
constexpr size_t OB_WBT = alup(OB_WB3 + (size_t)27*64*64*2);
constexpr size_t OB_WB5 = alup(OB_WBT + (size_t)27*64*64*2);

// ---------------- types / helpers ----------------
typedef __attribute__((ext_vector_type(8))) short short8;
typedef __attribute__((ext_vector_type(4))) float f32x4;

__device__ inline unsigned short f2bf(float f) {
  unsigned int u = __float_as_uint(f);
  u = (u + 0x7FFFu + ((u >> 16) & 1u)) >> 16;   // RNE
  return (unsigned short)u;
}

template<int DD>
__device__ inline void decodev(int vox, int& b, int& z, int& y, int& x) {
  x = vox % DD; int r = vox / DD;
  y = r % DD;   r /= DD;
  z = r % DD;   b = r / DD;
}

// ---------------- scatter ----------------
__global__ void k_scatter(const float* __restrict__ feat, const int* __restrict__ coors,
                          int n, float* __restrict__ x0, float* __restrict__ m0) {
  int i = blockIdx.x*blockDim.x + threadIdx.x;
  if (i >= n) return;
  int b = coors[4*i+0], z = coors[4*i+1], y = coors[4*i+2], x = coors[4*i+3];
  int v = ((b*DP + z)*DP + y)*DP + x;
  x0[v*3+0] = feat[3*i+0];
  x0[v*3+1] = feat[3*i+1];
  x0[v*3+2] = feat[3*i+2];
  m0[v] = 1.0f;
}

// ---------------- conv1: 3 -> 64, VALID, mask+act, bf16 out ----------------
__global__ void __launch_bounds__(256)
k_conv1(const float* __restrict__ x0, const float* __restrict__ m0,
        unsigned short* __restrict__ x1, float* __restrict__ m1p,
        const float* __restrict__ w1, const float* __restrict__ b1,
        const float* __restrict__ s1, const float* __restrict__ h1) {
  long long t = (long long)blockIdx.x*blockDim.x + threadIdx.x;
  if (t >= (long long)NV1*C) return;
  int co  = (int)(t & 63);
  int vox = (int)(t >> 6);
  int b, z, y, x; decodev<D1>(vox, b, z, y, x);
  float sum = 0.f, mm = 0.f;
  #pragma unroll
  for (int kz=0; kz<3; kz++)
  #pragma unroll
  for (int ky=0; ky<3; ky++)
  #pragma unroll
  for (int kx=0; kx<3; kx++) {
    int iv = ((b*DP + z+kz)*DP + y+ky)*DP + (x+kx);
    mm += m0[iv];
    const float* px = x0 + iv*3;
    const float* pw = w1 + ((kz*3+ky)*3+kx)*3*64 + co;
    sum += px[0]*pw[0] + px[1]*pw[64] + px[2]*pw[128];
  }
  bool m = mm > 0.f;
  float o = m ? fmaxf((sum + b1[co])*s1[co] + h1[co], 0.f) : 0.f;
  size_t pOff = (size_t)(((b*DP + z+1)*DP + y+1)*DP + (x+1));
  x1[pOff*C + co] = f2bf(o);
  if (co == 0) m1p[pOff] = m ? 1.f : 0.f;
}

// ---------------- weight repack into B-fragment lane order ----------------
// dst[((t*2+kk)*4+cb)*512 + l*8 + j] = bf16(w[t][k][co]),
//   k = kk*32 + (l>>4)*8 + j, co = cb*16 + (l&15)
__global__ void k_repack(const float* __restrict__ w, unsigned short* __restrict__ dst) {
  int i = blockIdx.x*256 + threadIdx.x;
  if (i >= 27*64*64) return;
  int co = i & 63, k = (i >> 6) & 63, t = i >> 12;
  int kk = k >> 5, q = (k >> 3) & 3, j = k & 7, cb = co >> 4, l = q*16 + (co & 15);
  dst[(size_t)((t*2+kk)*4+cb)*512 + l*8 + j] = f2bf(w[i]);
}

// ---------------- MFMA implicit-GEMM conv (3^3, 64->64) ----------------
// OUTMODE: 0 = padded bf16 + mask/act, 2 = NCDHW f32 (d_out) + act via LDS transpose
template<int NA, int DOUT, int DIN, int OUTMODE>
__global__ void __launch_bounds__(256)
k_conv_mfma(const unsigned short* __restrict__ inBF, const unsigned short* __restrict__ wB,
            void* __restrict__ outPtr, const float* __restrict__ m1p,
            const float* __restrict__ bias, const float* __restrict__ s,
            const float* __restrict__ h) {
  constexpr int NVOX = BB*DOUT*DOUT*DOUT;
  const int lane = threadIdx.x & 63;
  const int wid  = threadIdx.x >> 6;
  const int wave = blockIdx.x*4 + wid;
  const int vb   = wave * (NA*16);

  int rowb[NA];
  #pragma unroll
  for (int a = 0; a < NA; a++) {
    int vox = vb + a*16 + (lane & 15);
    vox = vox < NVOX ? vox : NVOX-1;
    int b, z, y, x; decodev<DOUT>(vox, b, z, y, x);
    rowb[a] = (((b*DIN + z)*DIN + y)*DIN + x)*64;
  }
  const int koff = (lane >> 4) * 8;

  f32x4 acc[NA][4];
  #pragma unroll
  for (int a = 0; a < NA; a++)
    #pragma unroll
    for (int cb = 0; cb < 4; cb++)
      acc[a][cb] = f32x4{0.f, 0.f, 0.f, 0.f};

  #pragma unroll 1
  for (int t = 0; t < 27; ++t) {
    int kz = t / 9, rr = t - kz*9;
    int ky = rr / 3, kx = rr - ky*3;
    const int toff = ((kz*DIN + ky)*DIN + kx)*64;
    #pragma unroll
    for (int kk = 0; kk < 2; ++kk) {
      short8 A[NA];
      #pragma unroll
      for (int a = 0; a < NA; a++)
        A[a] = *reinterpret_cast<const short8*>(inBF + rowb[a] + toff + kk*32 + koff);
      short8 Bv[4];
      const unsigned short* wp = wB + (size_t)(t*2+kk)*2048 + lane*8;
      #pragma unroll
      for (int cb = 0; cb < 4; cb++)
        Bv[cb] = *reinterpret_cast<const short8*>(wp + cb*512);
      #pragma unroll
      for (int a = 0; a < NA; a++)
        #pragma unroll
        for (int cb = 0; cb < 4; cb++)
          acc[a][cb] = __builtin_amdgcn_mfma_f32_16x16x32_bf16(A[a], Bv[cb], acc[a][cb], 0, 0, 0);
    }
  }

  float bv[4], sv[4], hv[4];
  #pragma unroll
  for (int cb = 0; cb < 4; cb++) {
    int c = cb*16 + (lane & 15);
    bv[cb] = bias[c]; sv[cb] = s[c]; hv[cb] = h[c];
  }

  if constexpr (OUTMODE == 2) {
    __shared__ float lds[4][32*65];
    float* L = lds[wid];
    float* out = (float*)outPtr;
    #pragma unroll
    for (int hh = 0; hh < 2; ++hh) {
      #pragma unroll
      for (int a2 = 0; a2 < 2; a2++) {
        int a = 2*hh + a2;
        #pragma unroll
        for (int cb = 0; cb < 4; cb++)
          #pragma unroll
          for (int r = 0; r < 4; r++) {
            float o = fmaxf((acc[a][cb][r] + bv[cb])*sv[cb] + hv[cb], 0.f);
            L[(a2*16 + (lane>>4)*4 + r)*65 + cb*16 + (lane & 15)] = o;
          }
      }
      __syncthreads();
      #pragma unroll 4
      for (int cc = 0; cc < 32; ++cc) {
        int co  = 2*cc + (lane >> 5);
        int vox = vb + hh*32 + (lane & 31);
        if (vox < NVOX) {
          float v = L[(lane & 31)*65 + co];
          int b = vox >= D5CUBE ? 1 : 0;
          out[(size_t)(b*64 + co)*D5CUBE + (vox - b*D5CUBE)] = v;
        }
      }
      __syncthreads();
    }
  } else {
    #pragma unroll
    for (int a = 0; a < NA; a++)
      #pragma unroll
      for (int r = 0; r < 4; r++) {
        int vox = vb + a*16 + (lane >> 4)*4 + r;
        if (vox >= NVOX) continue;
        int b, z, y, x; decodev<DOUT>(vox, b, z, y, x);
        size_t pOff = (size_t)(((b*DP + z+1)*DP + y+1)*DP + (x+1));
        bool m = m1p[pOff] > 0.f;
        #pragma unroll
        for (int cb = 0; cb < 4; cb++) {
          float o = m ? fmaxf((acc[a][cb][r] + bv[cb])*sv[cb] + hv[cb], 0.f) : 0.f;
          ((unsigned short*)outPtr)[pOff*64 + cb*16 + (lane & 15)] = f2bf(o);
        }
      }
  }
}

// ---------------- mT mask precompute (gather over padded m1) ----------------
__global__ void __launch_bounds__(256)
k_maskT(const float* __restrict__ m1p, float* __restrict__ mt) {
  int vox = blockIdx.x*256 + threadIdx.x;
  if (vox >= NV4) return;
  int b, zo, yo, xo; decodev<D4>(vox, b, zo, yo, xo);
  float mm = 0.f;
  for (int kz = 0; kz < 3; kz++) {
    if ((zo + kz) & 1) continue;
    int izp = ((zo + kz - 2) >> 1) + 1;
    for (int ky = 0; ky < 3; ky++) {
      if ((yo + ky) & 1) continue;
      int iyp = ((yo + ky - 2) >> 1) + 1;
      for (int kx = 0; kx < 3; kx++) {
        if ((xo + kx) & 1) continue;
        int ixp = ((xo + kx - 2) >> 1) + 1;
        mm += m1p[((b*DP + izp)*DP + iyp)*DP + ixp];
      }
    }
  }
  mt[vox] = mm;
}

// ---------------- conv_transpose stride2 VALID via MFMA (parity decomposition) ----------------
// wave = one output x-row (b, zo, yo); 4 A-fragments: {even-x, odd-x} x {block0, block1}
__global__ void __launch_bounds__(256)
k_convT_mfma(const unsigned short* __restrict__ x3, const unsigned short* __restrict__ wB,
             unsigned short* __restrict__ x4, const float* __restrict__ mt,
             const float* __restrict__ bias, const float* __restrict__ s,
             const float* __restrict__ h) {
  const int lane = threadIdx.x & 63;
  const int wid  = threadIdx.x >> 6;
  const int w    = blockIdx.x*4 + wid;
  if (w >= BB*D4*D4) return;
  const int b  = w / (D4*D4);
  const int rm = w % (D4*D4);
  const int zo = rm / D4;
  const int yo = rm % D4;
  const int ii = lane & 15;
  const int koff = (lane >> 4) * 8;

  f32x4 acc[4][4];
  #pragma unroll
  for (int a = 0; a < 4; a++)
    #pragma unroll
    for (int cb = 0; cb < 4; cb++)
      acc[a][cb] = f32x4{0.f, 0.f, 0.f, 0.f};

  #pragma unroll 1
  for (int kz = 0; kz < 3; kz++) {
    if ((zo + kz) & 1) continue;
    const int izp = ((zo + kz - 2) >> 1) + 1;
    #pragma unroll 1
    for (int ky = 0; ky < 3; ky++) {
      if ((yo + ky) & 1) continue;
      const int iyp = ((yo + ky - 2) >> 1) + 1;
      const size_t planeBase = ((size_t)((b*DP + izp)*DP + iyp))*DP*64;
      #pragma unroll
      for (int kx = 0; kx < 3; kx++) {
        const int apar  = kx & 1;                    // which x-parity fragments use this kx
        const int xoffE = ((kx + apar - 2) >> 1) + 1;
        const int t = (kz*3 + ky)*3 + kx;
        #pragma unroll
        for (int kk = 0; kk < 2; ++kk) {
          short8 Bv[4];
          const unsigned short* wpk = wB + (size_t)(t*2+kk)*2048 + lane*8;
          #pragma unroll
          for (int cb = 0; cb < 4; cb++)
            Bv[cb] = *reinterpret_cast<const short8*>(wpk + cb*512);
          #pragma unroll
          for (int ablk = 0; ablk < 2; ablk++) {
            const int ixp = ablk*16 + ii + xoffE;
            short8 A = *reinterpret_cast<const short8*>(x3 + planeBase + (size_t)ixp*64 + kk*32 + koff);
            const int afr = apar*2 + ablk;
            #pragma unroll
            for (int cb = 0; cb < 4; cb++)
              acc[afr][cb] = __builtin_amdgcn_mfma_f32_16x16x32_bf16(A, Bv[cb], acc[afr][cb], 0, 0, 0);
          }
        }
      }
    }
  }

  float bv[4], sv[4], hv[4];
  #pragma unroll
  for (int cb = 0; cb < 4; cb++) {
    int c = cb*16 + (lane & 15);
    bv[cb] = bias[c]; sv[cb] = s[c]; hv[cb] = h[c];
  }
  const int rowBase = ((b*D4 + zo)*D4 + yo)*D4;
  #pragma unroll
  for (int a = 0; a < 4; a++) {
    const int ablk = a & 1, apar = a >> 1;
    #pragma unroll
    for (int r = 0; r < 4; r++) {
      const int row = (lane >> 4)*4 + r;
      const int xo  = 2*(ablk*16 + row) + apar;
      if (xo >= D4) continue;
      const int vox = rowBase + xo;
      const bool m = mt[vox] > 0.f;
      #pragma unroll
      for (int cb = 0; cb < 4; cb++) {
        float o = m ? fmaxf((acc[a][cb][r] + bv[cb])*sv[cb] + hv[cb], 0.f) : 0.f;
        x4[(size_t)vox*64 + cb*16 + (lane & 15)] = f2bf(o);
      }
    }
  }
}

// ---------------- launcher ----------------
extern "C" void kernel_launch(void* const* d_in, const int* in_sizes, int n_in,
                              void* d_out, int out_size, void* d_ws, size_t ws_size,
                              hipStream_t stream) {
  const float* feat  = (const float*)d_in[0];
  const int*   coors = (const int*)d_in[1];
  const float* w1 = (const float*)d_in[3];
  const float* b1 = (const float*)d_in[4];
  const float* w2 = (const float*)d_in[5];
  const float* b2 = (const float*)d_in[6];
  const float* w3 = (const float*)d_in[7];
  const float* b3 = (const float*)d_in[8];
  const float* wt = (const float*)d_in[9];
  const float* bt = (const float*)d_in[10];
  const float* w5 = (const float*)d_in[11];
  const float* b5 = (const float*)d_in[12];
  const float* s1 = (const float*)d_in[13];
  const float* h1 = (const float*)d_in[14];
  const float* s2 = (const float*)d_in[15];
  const float* h2 = (const float*)d_in[16];
  const float* s3 = (const float*)d_in[17];
  const float* h3 = (const float*)d_in[18];
  const float* s4 = (const float*)d_in[19];
  const float* h4 = (const float*)d_in[20];
  const float* s5 = (const float*)d_in[21];
  const float* h5 = (const float*)d_in[22];
  int n = in_sizes[0] / 3;

  char* wsb = (char*)d_ws;
  float*          X0  = (float*)(wsb + OB_X0);
  float*          M0  = (float*)(wsb + OB_M0);
  float*          M1P = (float*)(wsb + OB_M1P);
  unsigned short* X1  = (unsigned short*)(wsb + OB_X1);
  unsigned short* X2  = (unsigned short*)(wsb + OB_X2);
  unsigned short* X3  = (unsigned short*)(wsb + OB_X3);
  float*          MT  = (float*)(wsb + OB_MT);
  unsigned short* X4  = (unsigned short*)(wsb + OB_X4);
  unsigned short* WB2 = (unsigned short*)(wsb + OB_WB2);
  unsigned short* WB3 = (unsigned short*)(wsb + OB_WB3);
  unsigned short* WBT = (unsigned short*)(wsb + OB_WBT);
  unsigned short* WB5 = (unsigned short*)(wsb + OB_WB5);

  // zero x0/m0/m1p and padded x1/x2/x3 (MT, X4, d_out fully rewritten each launch)
  hipMemsetAsync(wsb, 0, OB_MT, stream);

  k_repack<<<432, 256, 0, stream>>>(w2, WB2);
  k_repack<<<432, 256, 0, stream>>>(w3, WB3);
  k_repack<<<432, 256, 0, stream>>>(wt, WBT);
  k_repack<<<432, 256, 0, stream>>>(w5, WB5);

  k_scatter<<<(n+255)/256, 256, 0, stream>>>(feat, coors, n, X0, M0);

  {
    long long threads = (long long)NV1*C;
    k_conv1<<<(int)((threads+255)/256), 256, 0, stream>>>(X0, M0, X1, M1P, w1, b1, s1, h1);
  }

  constexpr int WAVES23 = (NV1 + 31) / 32;
  constexpr int BLK23   = (WAVES23 + 3) / 4;
  k_conv_mfma<2, D1, DP, 0><<<BLK23, 256, 0, stream>>>(X1, WB2, X2, M1P, b2, s2, h2);
  k_conv_mfma<2, D1, DP, 0><<<BLK23, 256, 0, stream>>>(X2, WB3, X3, M1P, b3, s3, h3);

  k_maskT<<<(NV4 + 255)/256, 256, 0, stream>>>(M1P, MT);

  constexpr int ROWS_T = BB*D4*D4;                // 7938
  k_convT_mfma<<<(ROWS_T + 3)/4, 256, 0, stream>>>(X3, WBT, X4, MT, bt, s4, h4);

  constexpr int WAVES5 = (NV5 + 63) / 64;
  constexpr int BLK5   = (WAVES5 + 3) / 4;
  k_conv_mfma<4, D5, D4, 2><<<BLK5, 256, 0, stream>>>(X4, WB5, d_out, nullptr, b5, s5, h5);
}

// Round 4
// 484.944 us; speedup vs baseline: 20.4439x; 1.0830x over previous
//
#include <hip/hip_runtime.h>
#include <cstdint>

// ---------------- geometry ----------------
constexpr int BB = 2, C = 64;
constexpr int D1 = 31;          // conv1 out / conv2,3 spatial
constexpr int DP = 33;          // padded spatial for x1..x3
constexpr int D4 = 63;          // conv_transpose out spatial
constexpr int D5 = 61;          // conv5 out spatial
constexpr int D5CUBE = D5*D5*D5;   // 226981

constexpr int NV1 = BB*D1*D1*D1;   // 59582
constexpr int NVP = BB*DP*DP*DP;   // 71874
constexpr int NV4 = BB*D4*D4*D4;   // 500094
constexpr int NV5 = BB*D5*D5*D5;   // 453962

// ---------------- workspace layout (byte offsets) ----------------
constexpr size_t alup(size_t x) { return (x + 255) & ~(size_t)255; }
constexpr size_t OB_X0  = 0;                                     // [NVP][3] f32
constexpr size_t OB_M0  = alup(OB_X0  + (size_t)NVP*3*4);        // [NVP] f32
constexpr size_t OB_M1P = alup(OB_M0  + (size_t)NVP*4);          // [NVP] f32 padded mask
constexpr size_t OB_X1  = alup(OB_M1P + (size_t)NVP*4);          // [NVP][64] bf16 padded
constexpr size_t OB_X2  = alup(OB_X1  + (size_t)NVP*64*2);       // [NVP][64] bf16 padded
constexpr size_t OB_X3  = alup(OB_X2  + (size_t)NVP*64*2);       // [NVP][64] bf16 padded
constexpr size_t OB_MT  = alup(OB_X3  + (size_t)NVP*64*2);       // [NV4] f32 (fully rewritten)
constexpr size_t OB_X4  = alup(OB_MT  + (size_t)NV4*4);          // [NV4][64] bf16 (fully rewritten)
constexpr size_t OB_WB2 = alup(OB_X4  + (size_t)NV4*64*2);
constexpr size_t OB_WB3 = alup(OB_WB2 + (size_t)27*64*64*2);
constexpr size_t OB_WBT = alup(OB_WB3 + (size_t)27*64*64*2);
constexpr size_t OB_WB5 = alup(OB_WBT + (size_t)27*64*64*2);

// ---------------- types / helpers ----------------
typedef __attribute__((ext_vector_type(8))) short short8;
typedef __attribute__((ext_vector_type(4))) float f32x4;

__device__ inline unsigned short f2bf(float f) {
  unsigned int u = __float_as_uint(f);
  u = (u + 0x7FFFu + ((u >> 16) & 1u)) >> 16;   // RNE
  return (unsigned short)u;
}

template<int DD>
__device__ inline void decodev(int vox, int& b, int& z, int& y, int& x) {
  x = vox % DD; int r = vox / DD;
  y = r % DD;   r /= DD;
  z = r % DD;   b = r / DD;
}

// bijective XCD-chunked block swizzle (m204): each XCD gets a contiguous chunk
__device__ inline int xcd_swz(int bid, int nb) {
  int q = nb >> 3, r = nb & 7;
  int xcd = bid & 7, idx = bid >> 3;
  return (xcd < r ? xcd*(q+1) : r*(q+1) + (xcd - r)*q) + idx;
}

// ---------------- scatter ----------------
__global__ void k_scatter(const float* __restrict__ feat, const int* __restrict__ coors,
                          int n, float* __restrict__ x0, float* __restrict__ m0) {
  int i = blockIdx.x*blockDim.x + threadIdx.x;
  if (i >= n) return;
  int b = coors[4*i+0], z = coors[4*i+1], y = coors[4*i+2], x = coors[4*i+3];
  int v = ((b*DP + z)*DP + y)*DP + x;
  x0[v*3+0] = feat[3*i+0];
  x0[v*3+1] = feat[3*i+1];
  x0[v*3+2] = feat[3*i+2];
  m0[v] = 1.0f;
}

// ---------------- conv1: 3 -> 64, VALID, mask+act, bf16 out ----------------
__global__ void __launch_bounds__(256)
k_conv1(const float* __restrict__ x0, const float* __restrict__ m0,
        unsigned short* __restrict__ x1, float* __restrict__ m1p,
        const float* __restrict__ w1, const float* __restrict__ b1,
        const float* __restrict__ s1, const float* __restrict__ h1) {
  long long t = (long long)blockIdx.x*blockDim.x + threadIdx.x;
  if (t >= (long long)NV1*C) return;
  int co  = (int)(t & 63);
  int vox = (int)(t >> 6);
  int b, z, y, x; decodev<D1>(vox, b, z, y, x);
  float sum = 0.f, mm = 0.f;
  #pragma unroll
  for (int kz=0; kz<3; kz++)
  #pragma unroll
  for (int ky=0; ky<3; ky++)
  #pragma unroll
  for (int kx=0; kx<3; kx++) {
    int iv = ((b*DP + z+kz)*DP + y+ky)*DP + (x+kx);
    mm += m0[iv];
    const float* px = x0 + iv*3;
    const float* pw = w1 + ((kz*3+ky)*3+kx)*3*64 + co;
    sum += px[0]*pw[0] + px[1]*pw[64] + px[2]*pw[128];
  }
  bool m = mm > 0.f;
  float o = m ? fmaxf((sum + b1[co])*s1[co] + h1[co], 0.f) : 0.f;
  size_t pOff = (size_t)(((b*DP + z+1)*DP + y+1)*DP + (x+1));
  x1[pOff*C + co] = f2bf(o);
  if (co == 0) m1p[pOff] = m ? 1.f : 0.f;
}

// ---------------- weight repack into MFMA fragment lane order ----------------
// dst[((t*2+kk)*4+cb)*512 + l*8 + j] = bf16(w[t][k][co]),
//   k = kk*32 + (l>>4)*8 + j, co = cb*16 + (l&15)
// Works for either operand slot (A/B lane maps are identical).
__global__ void k_repack(const float* __restrict__ w, unsigned short* __restrict__ dst) {
  int i = blockIdx.x*256 + threadIdx.x;
  if (i >= 27*64*64) return;
  int co = i & 63, k = (i >> 6) & 63, t = i >> 12;
  int kk = k >> 5, q = (k >> 3) & 3, j = k & 7, cb = co >> 4, l = q*16 + (co & 15);
  dst[(size_t)((t*2+kk)*4+cb)*512 + l*8 + j] = f2bf(w[i]);
}

// ---------------- MFMA implicit-GEMM conv (3^3, 64->64), padded bf16 out + mask/act ----------------
template<int NA, int DOUT, int DIN>
__global__ void __launch_bounds__(256)
k_conv_mfma(const unsigned short* __restrict__ inBF, const unsigned short* __restrict__ wB,
            unsigned short* __restrict__ outPtr, const float* __restrict__ m1p,
            const float* __restrict__ bias, const float* __restrict__ s,
            const float* __restrict__ h) {
  constexpr int NVOX = BB*DOUT*DOUT*DOUT;
  const int lane = threadIdx.x & 63;
  const int wid  = threadIdx.x >> 6;
  const int wave = xcd_swz(blockIdx.x, gridDim.x)*4 + wid;
  const int vb   = wave * (NA*16);

  int rowb[NA];
  #pragma unroll
  for (int a = 0; a < NA; a++) {
    int vox = vb + a*16 + (lane & 15);
    vox = vox < NVOX ? vox : NVOX-1;
    int b, z, y, x; decodev<DOUT>(vox, b, z, y, x);
    rowb[a] = (((b*DIN + z)*DIN + y)*DIN + x)*64;
  }
  const int koff = (lane >> 4) * 8;

  f32x4 acc[NA][4];
  #pragma unroll
  for (int a = 0; a < NA; a++)
    #pragma unroll
    for (int cb = 0; cb < 4; cb++)
      acc[a][cb] = f32x4{0.f, 0.f, 0.f, 0.f};

  #pragma unroll 1
  for (int t = 0; t < 27; ++t) {
    int kz = t / 9, rr = t - kz*9;
    int ky = rr / 3, kx = rr - ky*3;
    const int toff = ((kz*DIN + ky)*DIN + kx)*64;
    #pragma unroll
    for (int kk = 0; kk < 2; ++kk) {
      short8 A[NA];
      #pragma unroll
      for (int a = 0; a < NA; a++)
        A[a] = *reinterpret_cast<const short8*>(inBF + rowb[a] + toff + kk*32 + koff);
      short8 Bv[4];
      const unsigned short* wp = wB + (size_t)(t*2+kk)*2048 + lane*8;
      #pragma unroll
      for (int cb = 0; cb < 4; cb++)
        Bv[cb] = *reinterpret_cast<const short8*>(wp + cb*512);
      #pragma unroll
      for (int a = 0; a < NA; a++)
        #pragma unroll
        for (int cb = 0; cb < 4; cb++)
          acc[a][cb] = __builtin_amdgcn_mfma_f32_16x16x32_bf16(A[a], Bv[cb], acc[a][cb], 0, 0, 0);
    }
  }

  float bv[4], sv[4], hv[4];
  #pragma unroll
  for (int cb = 0; cb < 4; cb++) {
    int c = cb*16 + (lane & 15);
    bv[cb] = bias[c]; sv[cb] = s[c]; hv[cb] = h[c];
  }

  #pragma unroll
  for (int a = 0; a < NA; a++)
    #pragma unroll
    for (int r = 0; r < 4; r++) {
      int vox = vb + a*16 + (lane >> 4)*4 + r;
      if (vox >= NVOX) continue;
      int b, z, y, x; decodev<DOUT>(vox, b, z, y, x);
      size_t pOff = (size_t)(((b*DP + z+1)*DP + y+1)*DP + (x+1));
      bool m = m1p[pOff] > 0.f;
      #pragma unroll
      for (int cb = 0; cb < 4; cb++) {
        float o = m ? fmaxf((acc[a][cb][r] + bv[cb])*sv[cb] + hv[cb], 0.f) : 0.f;
        outPtr[pOff*64 + cb*16 + (lane & 15)] = f2bf(o);
      }
    }
}

// ---------------- mT mask precompute ----------------
__global__ void __launch_bounds__(256)
k_maskT(const float* __restrict__ m1p, float* __restrict__ mt) {
  int vox = blockIdx.x*256 + threadIdx.x;
  if (vox >= NV4) return;
  int b, zo, yo, xo; decodev<D4>(vox, b, zo, yo, xo);
  float mm = 0.f;
  for (int kz = 0; kz < 3; kz++) {
    if ((zo + kz) & 1) continue;
    int izp = ((zo + kz - 2) >> 1) + 1;
    for (int ky = 0; ky < 3; ky++) {
      if ((yo + ky) & 1) continue;
      int iyp = ((yo + ky - 2) >> 1) + 1;
      for (int kx = 0; kx < 3; kx++) {
        if ((xo + kx) & 1) continue;
        int ixp = ((xo + kx - 2) >> 1) + 1;
        mm += m1p[((b*DP + izp)*DP + iyp)*DP + ixp];
      }
    }
  }
  mt[vox] = mm;
}

// ---------------- conv_transpose stride2 VALID via MFMA (parity decomposition) ----------------
__global__ void __launch_bounds__(256)
k_convT_mfma(const unsigned short* __restrict__ x3, const unsigned short* __restrict__ wB,
             unsigned short* __restrict__ x4, const float* __restrict__ mt,
             const float* __restrict__ bias, const float* __restrict__ s,
             const float* __restrict__ h) {
  const int lane = threadIdx.x & 63;
  const int wid  = threadIdx.x >> 6;
  const int w    = xcd_swz(blockIdx.x, gridDim.x)*4 + wid;
  if (w >= BB*D4*D4) return;
  const int b  = w / (D4*D4);
  const int rm = w % (D4*D4);
  const int zo = rm / D4;
  const int yo = rm % D4;
  const int ii = lane & 15;
  const int koff = (lane >> 4) * 8;

  f32x4 acc[4][4];
  #pragma unroll
  for (int a = 0; a < 4; a++)
    #pragma unroll
    for (int cb = 0; cb < 4; cb++)
      acc[a][cb] = f32x4{0.f, 0.f, 0.f, 0.f};

  #pragma unroll 1
  for (int kz = 0; kz < 3; kz++) {
    if ((zo + kz) & 1) continue;
    const int izp = ((zo + kz - 2) >> 1) + 1;
    #pragma unroll 1
    for (int ky = 0; ky < 3; ky++) {
      if ((yo + ky) & 1) continue;
      const int iyp = ((yo + ky - 2) >> 1) + 1;
      const size_t planeBase = ((size_t)((b*DP + izp)*DP + iyp))*DP*64;
      #pragma unroll
      for (int kx = 0; kx < 3; kx++) {
        const int apar  = kx & 1;
        const int xoffE = ((kx + apar - 2) >> 1) + 1;
        const int t = (kz*3 + ky)*3 + kx;
        #pragma unroll
        for (int kk = 0; kk < 2; ++kk) {
          short8 Bv[4];
          const unsigned short* wpk = wB + (size_t)(t*2+kk)*2048 + lane*8;
          #pragma unroll
          for (int cb = 0; cb < 4; cb++)
            Bv[cb] = *reinterpret_cast<const short8*>(wpk + cb*512);
          #pragma unroll
          for (int ablk = 0; ablk < 2; ablk++) {
            const int ixp = ablk*16 + ii + xoffE;
            short8 A = *reinterpret_cast<const short8*>(x3 + planeBase + (size_t)ixp*64 + kk*32 + koff);
            const int afr = apar*2 + ablk;
            #pragma unroll
            for (int cb = 0; cb < 4; cb++)
              acc[afr][cb] = __builtin_amdgcn_mfma_f32_16x16x32_bf16(A, Bv[cb], acc[afr][cb], 0, 0, 0);
          }
        }
      }
    }
  }

  float bv[4], sv[4], hv[4];
  #pragma unroll
  for (int cb = 0; cb < 4; cb++) {
    int c = cb*16 + (lane & 15);
    bv[cb] = bias[c]; sv[cb] = s[c]; hv[cb] = h[c];
  }
  const int rowBase = ((b*D4 + zo)*D4 + yo)*D4;
  #pragma unroll
  for (int a = 0; a < 4; a++) {
    const int ablk = a & 1, apar = a >> 1;
    #pragma unroll
    for (int r = 0; r < 4; r++) {
      const int row = (lane >> 4)*4 + r;
      const int xo  = 2*(ablk*16 + row) + apar;
      if (xo >= D4) continue;
      const int vox = rowBase + xo;
      const bool m = mt[vox] > 0.f;
      #pragma unroll
      for (int cb = 0; cb < 4; cb++) {
        float o = m ? fmaxf((acc[a][cb][r] + bv[cb])*sv[cb] + hv[cb], 0.f) : 0.f;
        x4[(size_t)vox*64 + cb*16 + (lane & 15)] = f2bf(o);
      }
    }
  }
}

// ---------------- conv5: swapped-operand MFMA, no LDS, pipelined K-loop ----------------
__device__ __forceinline__ void c5_load(int ss, int koff, int lane,
    const unsigned short* __restrict__ x4, const unsigned short* __restrict__ wB,
    const int (&rowb)[4], short8 (&A)[4], short8 (&W)[4]) {
  const int t  = ss >> 1, kk = ss & 1;
  const int kz = t / 9, rr = t - kz*9;
  const int ky = rr / 3, kx = rr - ky*3;
  const int toff = ((kz*D4 + ky)*D4 + kx)*64 + kk*32 + koff;
  #pragma unroll
  for (int a = 0; a < 4; a++)
    A[a] = *reinterpret_cast<const short8*>(x4 + rowb[a] + toff);
  const unsigned short* wp = wB + (size_t)ss*2048 + lane*8;
  #pragma unroll
  for (int cb = 0; cb < 4; cb++)
    W[cb] = *reinterpret_cast<const short8*>(wp + cb*512);
}

__device__ __forceinline__ void c5_step(const short8 (&A)[4], const short8 (&W)[4],
                                        f32x4 (&acc)[4][4]) {
  #pragma unroll
  for (int a = 0; a < 4; a++)
    #pragma unroll
    for (int cb = 0; cb < 4; cb++)
      acc[a][cb] = __builtin_amdgcn_mfma_f32_16x16x32_bf16(W[cb], A[a], acc[a][cb], 0, 0, 0);
}

__global__ void __launch_bounds__(256, 2)
k_conv5_mfma(const unsigned short* __restrict__ x4, const unsigned short* __restrict__ wB,
             float* __restrict__ out, const float* __restrict__ bias,
             const float* __restrict__ s, const float* __restrict__ h) {
  const int lane = threadIdx.x & 63;
  const int wid  = threadIdx.x >> 6;
  const int wave = xcd_swz(blockIdx.x, gridDim.x)*4 + wid;
  const int vb   = wave * 64;
  const int koff = (lane >> 4) * 8;

  int rowb[4];
  #pragma unroll
  for (int a = 0; a < 4; a++) {
    int vox = vb + a*16 + (lane & 15);
    vox = vox < NV5 ? vox : NV5-1;
    int b, z, y, x; decodev<D5>(vox, b, z, y, x);
    rowb[a] = (((b*D4 + z)*D4 + y)*D4 + x)*64;
  }

  f32x4 acc[4][4];
  #pragma unroll
  for (int a = 0; a < 4; a++)
    #pragma unroll
    for (int cb = 0; cb < 4; cb++)
      acc[a][cb] = f32x4{0.f, 0.f, 0.f, 0.f};

  short8 A0[4], W0[4], A1[4], W1[4];
  c5_load(0, koff, lane, x4, wB, rowb, A0, W0);
  #pragma unroll 1
  for (int ss = 0; ss < 54; ss += 2) {
    c5_load(ss+1, koff, lane, x4, wB, rowb, A1, W1);   // prefetch odd step
    c5_step(A0, W0, acc);
    if (ss + 2 < 54)
      c5_load(ss+2, koff, lane, x4, wB, rowb, A0, W0); // prefetch next even step
    c5_step(A1, W1, acc);
  }

  // D: row = co = cb*16 + (lane>>4)*4 + r, col = vox = vb + a*16 + (lane&15)
  #pragma unroll
  for (int a = 0; a < 4; a++) {
    int vox = vb + a*16 + (lane & 15);
    if (vox >= NV5) continue;
    int bb2  = vox >= D5CUBE ? 1 : 0;
    int rvox = vox - bb2*D5CUBE;
    #pragma unroll
    for (int cb = 0; cb < 4; cb++)
      #pragma unroll
      for (int r = 0; r < 4; r++) {
        int co = cb*16 + (lane >> 4)*4 + r;
        float o = fmaxf((acc[a][cb][r] + bias[co])*s[co] + h[co], 0.f);
        out[(size_t)(bb2*64 + co)*D5CUBE + rvox] = o;
      }
  }
}

// ---------------- launcher ----------------
extern "C" void kernel_launch(void* const* d_in, const int* in_sizes, int n_in,
                              void* d_out, int out_size, void* d_ws, size_t ws_size,
                              hipStream_t stream) {
  const float* feat  = (const float*)d_in[0];
  const int*   coors = (const int*)d_in[1];
  const float* w1 = (const float*)d_in[3];
  const float* b1 = (const float*)d_in[4];
  const float* w2 = (const float*)d_in[5];
  const float* b2 = (const float*)d_in[6];
  const float* w3 = (const float*)d_in[7];
  const float* b3 = (const float*)d_in[8];
  const float* wt = (const float*)d_in[9];
  const float* bt = (const float*)d_in[10];
  const float* w5 = (const float*)d_in[11];
  const float* b5 = (const float*)d_in[12];
  const float* s1 = (const float*)d_in[13];
  const float* h1 = (const float*)d_in[14];
  const float* s2 = (const float*)d_in[15];
  const float* h2 = (const float*)d_in[16];
  const float* s3 = (const float*)d_in[17];
  const float* h3 = (const float*)d_in[18];
  const float* s4 = (const float*)d_in[19];
  const float* h4 = (const float*)d_in[20];
  const float* s5 = (const float*)d_in[21];
  const float* h5 = (const float*)d_in[22];
  int n = in_sizes[0] / 3;

  char* wsb = (char*)d_ws;
  float*          X0  = (float*)(wsb + OB_X0);
  float*          M0  = (float*)(wsb + OB_M0);
  float*          M1P = (float*)(wsb + OB_M1P);
  unsigned short* X1  = (unsigned short*)(wsb + OB_X1);
  unsigned short* X2  = (unsigned short*)(wsb + OB_X2);
  unsigned short* X3  = (unsigned short*)(wsb + OB_X3);
  float*          MT  = (float*)(wsb + OB_MT);
  unsigned short* X4  = (unsigned short*)(wsb + OB_X4);
  unsigned short* WB2 = (unsigned short*)(wsb + OB_WB2);
  unsigned short* WB3 = (unsigned short*)(wsb + OB_WB3);
  unsigned short* WBT = (unsigned short*)(wsb + OB_WBT);
  unsigned short* WB5 = (unsigned short*)(wsb + OB_WB5);

  hipMemsetAsync(wsb, 0, OB_MT, stream);

  k_repack<<<432, 256, 0, stream>>>(w2, WB2);
  k_repack<<<432, 256, 0, stream>>>(w3, WB3);
  k_repack<<<432, 256, 0, stream>>>(wt, WBT);
  k_repack<<<432, 256, 0, stream>>>(w5, WB5);

  k_scatter<<<(n+255)/256, 256, 0, stream>>>(feat, coors, n, X0, M0);

  {
    long long threads = (long long)NV1*C;
    k_conv1<<<(int)((threads+255)/256), 256, 0, stream>>>(X0, M0, X1, M1P, w1, b1, s1, h1);
  }

  constexpr int WAVES23 = (NV1 + 31) / 32;
  constexpr int BLK23   = (WAVES23 + 3) / 4;
  k_conv_mfma<2, D1, DP><<<BLK23, 256, 0, stream>>>(X1, WB2, X2, M1P, b2, s2, h2);
  k_conv_mfma<2, D1, DP><<<BLK23, 256, 0, stream>>>(X2, WB3, X3, M1P, b3, s3, h3);

  k_maskT<<<(NV4 + 255)/256, 256, 0, stream>>>(M1P, MT);

  constexpr int ROWS_T = BB*D4*D4;                // 7938
  k_convT_mfma<<<(ROWS_T + 3)/4, 256, 0, stream>>>(X3, WBT, X4, MT, bt, s4, h4);

  constexpr int WAVES5 = (NV5 + 63) / 64;         // 7094
  constexpr int BLK5   = (WAVES5 + 3) / 4;        // 1774
  k_conv5_mfma<<<BLK5, 256, 0, stream>>>(X4, WB5, (float*)d_out, b5, s5, h5);
}

// Round 5
// 377.249 us; speedup vs baseline: 26.2801x; 1.2855x over previous
//
#include <hip/hip_runtime.h>
#include <cstdint>

// ---------------- geometry ----------------
constexpr int BB = 2, C = 64;
constexpr int D1 = 31;          // conv1 out / conv2,3 spatial
constexpr int DP = 33;          // padded spatial for x1..x3
constexpr int D4 = 63;          // conv_transpose out spatial
constexpr int D5 = 61;          // conv5 out spatial
constexpr int D5CUBE = D5*D5*D5;   // 226981

constexpr int NV1 = BB*D1*D1*D1;   // 59582
constexpr int NVP = BB*DP*DP*DP;   // 71874
constexpr int NV4 = BB*D4*D4*D4;   // 500094
constexpr int NV5 = BB*D5*D5*D5;   // 453962

// ---------------- workspace layout (byte offsets) ----------------
constexpr size_t alup(size_t x) { return (x + 255) & ~(size_t)255; }
constexpr size_t OB_X0  = 0;                                     // [NVP][3] f32
constexpr size_t OB_M0  = alup(OB_X0  + (size_t)NVP*3*4);        // [NVP] f32
constexpr size_t OB_M1P = alup(OB_M0  + (size_t)NVP*4);          // [NVP] f32 padded mask
constexpr size_t OB_X1  = alup(OB_M1P + (size_t)NVP*4);          // [NVP][64] bf16 padded
constexpr size_t OB_X2  = alup(OB_X1  + (size_t)NVP*64*2);       // [NVP][64] bf16 padded
constexpr size_t OB_X3  = alup(OB_X2  + (size_t)NVP*64*2);       // [NVP][64] bf16 padded
constexpr size_t OB_MT  = alup(OB_X3  + (size_t)NVP*64*2);       // [NV4] f32 (fully rewritten)
constexpr size_t OB_X4  = alup(OB_MT  + (size_t)NV4*4);          // [NV4][64] bf16 (fully rewritten)
constexpr size_t OB_WB2 = alup(OB_X4  + (size_t)NV4*64*2);
constexpr size_t OB_WB3 = alup(OB_WB2 + (size_t)27*64*64*2);
constexpr size_t OB_WBT = alup(OB_WB3 + (size_t)27*64*64*2);
constexpr size_t OB_WB5 = alup(OB_WBT + (size_t)27*64*64*2);

// ---------------- types / helpers ----------------
typedef __attribute__((ext_vector_type(8))) short short8;
typedef __attribute__((ext_vector_type(4))) float f32x4;

__device__ inline unsigned short f2bf(float f) {
  unsigned int u = __float_as_uint(f);
  u = (u + 0x7FFFu + ((u >> 16) & 1u)) >> 16;   // RNE
  return (unsigned short)u;
}

template<int DD>
__device__ inline void decodev(int vox, int& b, int& z, int& y, int& x) {
  x = vox % DD; int r = vox / DD;
  y = r % DD;   r /= DD;
  z = r % DD;   b = r / DD;
}

// bijective XCD-chunked block swizzle (m204): each XCD gets a contiguous chunk
__device__ inline int xcd_swz(int bid, int nb) {
  int q = nb >> 3, r = nb & 7;
  int xcd = bid & 7, idx = bid >> 3;
  return (xcd < r ? xcd*(q+1) : r*(q+1) + (xcd - r)*q) + idx;
}

// ---------------- scatter ----------------
__global__ void k_scatter(const float* __restrict__ feat, const int* __restrict__ coors,
                          int n, float* __restrict__ x0, float* __restrict__ m0) {
  int i = blockIdx.x*blockDim.x + threadIdx.x;
  if (i >= n) return;
  int b = coors[4*i+0], z = coors[4*i+1], y = coors[4*i+2], x = coors[4*i+3];
  int v = ((b*DP + z)*DP + y)*DP + x;
  x0[v*3+0] = feat[3*i+0];
  x0[v*3+1] = feat[3*i+1];
  x0[v*3+2] = feat[3*i+2];
  m0[v] = 1.0f;
}

// ---------------- conv1: 3 -> 64, VALID, mask+act, bf16 out ----------------
__global__ void __launch_bounds__(256)
k_conv1(const float* __restrict__ x0, const float* __restrict__ m0,
        unsigned short* __restrict__ x1, float* __restrict__ m1p,
        const float* __restrict__ w1, const float* __restrict__ b1,
        const float* __restrict__ s1, const float* __restrict__ h1) {
  long long t = (long long)blockIdx.x*blockDim.x + threadIdx.x;
  if (t >= (long long)NV1*C) return;
  int co  = (int)(t & 63);
  int vox = (int)(t >> 6);
  int b, z, y, x; decodev<D1>(vox, b, z, y, x);
  float sum = 0.f, mm = 0.f;
  #pragma unroll
  for (int kz=0; kz<3; kz++)
  #pragma unroll
  for (int ky=0; ky<3; ky++)
  #pragma unroll
  for (int kx=0; kx<3; kx++) {
    int iv = ((b*DP + z+kz)*DP + y+ky)*DP + (x+kx);
    mm += m0[iv];
    const float* px = x0 + iv*3;
    const float* pw = w1 + ((kz*3+ky)*3+kx)*3*64 + co;
    sum += px[0]*pw[0] + px[1]*pw[64] + px[2]*pw[128];
  }
  bool m = mm > 0.f;
  float o = m ? fmaxf((sum + b1[co])*s1[co] + h1[co], 0.f) : 0.f;
  size_t pOff = (size_t)(((b*DP + z+1)*DP + y+1)*DP + (x+1));
  x1[pOff*C + co] = f2bf(o);
  if (co == 0) m1p[pOff] = m ? 1.f : 0.f;
}

// ---------------- weight repack into MFMA fragment lane order ----------------
// dst[((t*2+kk)*4+cb)*512 + l*8 + j] = bf16(w[t][k][co]),
//   k = kk*32 + (l>>4)*8 + j, co = cb*16 + (l&15)
__global__ void k_repack(const float* __restrict__ w, unsigned short* __restrict__ dst) {
  int i = blockIdx.x*256 + threadIdx.x;
  if (i >= 27*64*64) return;
  int co = i & 63, k = (i >> 6) & 63, t = i >> 12;
  int kk = k >> 5, q = (k >> 3) & 3, j = k & 7, cb = co >> 4, l = q*16 + (co & 15);
  dst[(size_t)((t*2+kk)*4+cb)*512 + l*8 + j] = f2bf(w[i]);
}

// ---------------- MFMA implicit-GEMM conv (3^3, 64->64), padded bf16 out + mask/act ----------------
template<int NA, int DOUT, int DIN>
__global__ void __launch_bounds__(256)
k_conv_mfma(const unsigned short* __restrict__ inBF, const unsigned short* __restrict__ wB,
            unsigned short* __restrict__ outPtr, const float* __restrict__ m1p,
            const float* __restrict__ bias, const float* __restrict__ s,
            const float* __restrict__ h) {
  constexpr int NVOX = BB*DOUT*DOUT*DOUT;
  const int lane = threadIdx.x & 63;
  const int wid  = threadIdx.x >> 6;
  const int wave = xcd_swz(blockIdx.x, gridDim.x)*4 + wid;
  const int vb   = wave * (NA*16);

  int rowb[NA];
  #pragma unroll
  for (int a = 0; a < NA; a++) {
    int vox = vb + a*16 + (lane & 15);
    vox = vox < NVOX ? vox : NVOX-1;
    int b, z, y, x; decodev<DOUT>(vox, b, z, y, x);
    rowb[a] = (((b*DIN + z)*DIN + y)*DIN + x)*64;
  }
  const int koff = (lane >> 4) * 8;

  f32x4 acc[NA][4];
  #pragma unroll
  for (int a = 0; a < NA; a++)
    #pragma unroll
    for (int cb = 0; cb < 4; cb++)
      acc[a][cb] = f32x4{0.f, 0.f, 0.f, 0.f};

  #pragma unroll 1
  for (int t = 0; t < 27; ++t) {
    int kz = t / 9, rr = t - kz*9;
    int ky = rr / 3, kx = rr - ky*3;
    const int toff = ((kz*DIN + ky)*DIN + kx)*64;
    #pragma unroll
    for (int kk = 0; kk < 2; ++kk) {
      short8 A[NA];
      #pragma unroll
      for (int a = 0; a < NA; a++)
        A[a] = *reinterpret_cast<const short8*>(inBF + rowb[a] + toff + kk*32 + koff);
      short8 Bv[4];
      const unsigned short* wp = wB + (size_t)(t*2+kk)*2048 + lane*8;
      #pragma unroll
      for (int cb = 0; cb < 4; cb++)
        Bv[cb] = *reinterpret_cast<const short8*>(wp + cb*512);
      #pragma unroll
      for (int a = 0; a < NA; a++)
        #pragma unroll
        for (int cb = 0; cb < 4; cb++)
          acc[a][cb] = __builtin_amdgcn_mfma_f32_16x16x32_bf16(A[a], Bv[cb], acc[a][cb], 0, 0, 0);
    }
  }

  float bv[4], sv[4], hv[4];
  #pragma unroll
  for (int cb = 0; cb < 4; cb++) {
    int c = cb*16 + (lane & 15);
    bv[cb] = bias[c]; sv[cb] = s[c]; hv[cb] = h[c];
  }

  #pragma unroll
  for (int a = 0; a < NA; a++)
    #pragma unroll
    for (int r = 0; r < 4; r++) {
      int vox = vb + a*16 + (lane >> 4)*4 + r;
      if (vox >= NVOX) continue;
      int b, z, y, x; decodev<DOUT>(vox, b, z, y, x);
      size_t pOff = (size_t)(((b*DP + z+1)*DP + y+1)*DP + (x+1));
      bool m = m1p[pOff] > 0.f;
      #pragma unroll
      for (int cb = 0; cb < 4; cb++) {
        float o = m ? fmaxf((acc[a][cb][r] + bv[cb])*sv[cb] + hv[cb], 0.f) : 0.f;
        outPtr[pOff*64 + cb*16 + (lane & 15)] = f2bf(o);
      }
    }
}

// ---------------- mT mask precompute ----------------
__global__ void __launch_bounds__(256)
k_maskT(const float* __restrict__ m1p, float* __restrict__ mt) {
  int vox = blockIdx.x*256 + threadIdx.x;
  if (vox >= NV4) return;
  int b, zo, yo, xo; decodev<D4>(vox, b, zo, yo, xo);
  float mm = 0.f;
  for (int kz = 0; kz < 3; kz++) {
    if ((zo + kz) & 1) continue;
    int izp = ((zo + kz - 2) >> 1) + 1;
    for (int ky = 0; ky < 3; ky++) {
      if ((yo + ky) & 1) continue;
      int iyp = ((yo + ky - 2) >> 1) + 1;
      for (int kx = 0; kx < 3; kx++) {
        if ((xo + kx) & 1) continue;
        int ixp = ((xo + kx - 2) >> 1) + 1;
        mm += m1p[((b*DP + izp)*DP + iyp)*DP + ixp];
      }
    }
  }
  mt[vox] = mm;
}

// ---------------- conv_transpose stride2 VALID via MFMA (parity decomposition) ----------------
__global__ void __launch_bounds__(256)
k_convT_mfma(const unsigned short* __restrict__ x3, const unsigned short* __restrict__ wB,
             unsigned short* __restrict__ x4, const float* __restrict__ mt,
             const float* __restrict__ bias, const float* __restrict__ s,
             const float* __restrict__ h) {
  const int lane = threadIdx.x & 63;
  const int wid  = threadIdx.x >> 6;
  const int w    = xcd_swz(blockIdx.x, gridDim.x)*4 + wid;
  if (w >= BB*D4*D4) return;
  const int b  = w / (D4*D4);
  const int rm = w % (D4*D4);
  const int zo = rm / D4;
  const int yo = rm % D4;
  const int ii = lane & 15;
  const int koff = (lane >> 4) * 8;

  f32x4 acc[4][4];
  #pragma unroll
  for (int a = 0; a < 4; a++)
    #pragma unroll
    for (int cb = 0; cb < 4; cb++)
      acc[a][cb] = f32x4{0.f, 0.f, 0.f, 0.f};

  #pragma unroll 1
  for (int kz = 0; kz < 3; kz++) {
    if ((zo + kz) & 1) continue;
    const int izp = ((zo + kz - 2) >> 1) + 1;
    #pragma unroll 1
    for (int ky = 0; ky < 3; ky++) {
      if ((yo + ky) & 1) continue;
      const int iyp = ((yo + ky - 2) >> 1) + 1;
      const size_t planeBase = ((size_t)((b*DP + izp)*DP + iyp))*DP*64;
      #pragma unroll
      for (int kx = 0; kx < 3; kx++) {
        const int apar  = kx & 1;
        const int xoffE = ((kx + apar - 2) >> 1) + 1;
        const int t = (kz*3 + ky)*3 + kx;
        #pragma unroll
        for (int kk = 0; kk < 2; ++kk) {
          short8 Bv[4];
          const unsigned short* wpk = wB + (size_t)(t*2+kk)*2048 + lane*8;
          #pragma unroll
          for (int cb = 0; cb < 4; cb++)
            Bv[cb] = *reinterpret_cast<const short8*>(wpk + cb*512);
          #pragma unroll
          for (int ablk = 0; ablk < 2; ablk++) {
            const int ixp = ablk*16 + ii + xoffE;
            short8 A = *reinterpret_cast<const short8*>(x3 + planeBase + (size_t)ixp*64 + kk*32 + koff);
            const int afr = apar*2 + ablk;
            #pragma unroll
            for (int cb = 0; cb < 4; cb++)
              acc[afr][cb] = __builtin_amdgcn_mfma_f32_16x16x32_bf16(A, Bv[cb], acc[afr][cb], 0, 0, 0);
          }
        }
      }
    }
  }

  float bv[4], sv[4], hv[4];
  #pragma unroll
  for (int cb = 0; cb < 4; cb++) {
    int c = cb*16 + (lane & 15);
    bv[cb] = bias[c]; sv[cb] = s[c]; hv[cb] = h[c];
  }
  const int rowBase = ((b*D4 + zo)*D4 + yo)*D4;
  #pragma unroll
  for (int a = 0; a < 4; a++) {
    const int ablk = a & 1, apar = a >> 1;
    #pragma unroll
    for (int r = 0; r < 4; r++) {
      const int row = (lane >> 4)*4 + r;
      const int xo  = 2*(ablk*16 + row) + apar;
      if (xo >= D4) continue;
      const int vox = rowBase + xo;
      const bool m = mt[vox] > 0.f;
      #pragma unroll
      for (int cb = 0; cb < 4; cb++) {
        float o = m ? fmaxf((acc[a][cb][r] + bv[cb])*sv[cb] + hv[cb], 0.f) : 0.f;
        x4[(size_t)vox*64 + cb*16 + (lane & 15)] = f2bf(o);
      }
    }
  }
}

// ---------------- conv5: LDS-staged tile kernel ----------------
// Block = 4 waves = out rows (b, z, y0..y0+3), 61 x, 64 co.
// Per kz-phase: DMA-stage 6 input rows (63 vox x 128B) into LDS, then 18 MFMA steps.
// LDS chunk swizzle: logical chunk c (16B, 8/voxel-row) stored at phys c ^ (v&7);
// DMA dest linear, source pre-swizzled; ds_read applies same XOR (rule #21).
constexpr int C5_CHUNKS = 3072;   // 12 iters * 256 threads (6*63*8 = 3024 used + pad)

__device__ __forceinline__ void c5_ldW(const unsigned short* __restrict__ wB, int wslot,
                                       int lane, short8 (&W)[4]) {
  const unsigned short* wp = wB + (size_t)wslot*2048 + lane*8;
  #pragma unroll
  for (int cb = 0; cb < 4; cb++)
    W[cb] = *reinterpret_cast<const short8*>(wp + cb*512);
}

__device__ __forceinline__ void c5_ldA(const short8* __restrict__ sb, int rb, int kx,
                                       int kkc, int l16, const int (&va)[4], short8 (&A)[4]) {
  #pragma unroll
  for (int a = 0; a < 4; a++) {
    int v  = va[a] + kx;
    int ch = ((rb + v) << 3) + ((kkc + l16) ^ (v & 7));
    A[a] = sb[ch];
  }
}

__device__ __forceinline__ void c5_step(const short8 (&A)[4], const short8 (&W)[4],
                                        f32x4 (&acc)[4][4]) {
  #pragma unroll
  for (int a = 0; a < 4; a++)
    #pragma unroll
    for (int cb = 0; cb < 4; cb++)
      acc[a][cb] = __builtin_amdgcn_mfma_f32_16x16x32_bf16(W[cb], A[a], acc[a][cb], 0, 0, 0);
}

__global__ void __launch_bounds__(256, 3)
k_conv5_mfma(const unsigned short* __restrict__ x4, const unsigned short* __restrict__ wB,
             float* __restrict__ out, const float* __restrict__ bias,
             const float* __restrict__ s, const float* __restrict__ h) {
  __shared__ short8 sbuf[C5_CHUNKS];
  const int tid  = threadIdx.x;
  const int lane = tid & 63;
  const int wid  = tid >> 6;          // out-row j within tile
  const int ll   = lane & 15;
  const int l16  = lane >> 4;

  const int blk   = xcd_swz(blockIdx.x, gridDim.x);
  const int ytile = blk & 15;         // 16 y-tiles (bijective: grid = BB*D5*16, %8==0)
  const int rzb   = blk >> 4;
  const int z     = rzb % D5;
  const int b     = rzb / D5;
  const int y0    = ytile * 4;

  // per-thread stage source offsets (within a z-plane), pre-swizzled
  int srcoff[12];
  #pragma unroll
  for (int it = 0; it < 12; ++it) {
    int g = it*256 + tid; if (g >= 3024) g -= 3024;
    int r = g / 504, rem = g - r*504;          // 504 chunks per staged row
    int v = rem >> 3, c16p = rem & 7;
    int c16l = c16p ^ (v & 7);                  // logical chunk stored at phys c16p
    int yin = y0 + r; yin = yin > D4-1 ? D4-1 : yin;
    srcoff[it] = ((yin*D4 + v) << 7) + (c16l << 4);
  }

  int va[4];
  #pragma unroll
  for (int a = 0; a < 4; a++) va[a] = a*16 + ll;

  f32x4 acc[4][4];
  #pragma unroll
  for (int a = 0; a < 4; a++)
    #pragma unroll
    for (int cb = 0; cb < 4; cb++)
      acc[a][cb] = f32x4{0.f, 0.f, 0.f, 0.f};

  const char* x4b = (const char*)x4;
  char* lbase = (char*)&sbuf[0];

  #pragma unroll 1
  for (int kz = 0; kz < 3; ++kz) {
    // ---- stage 6 input rows of plane z+kz (48KB) via global->LDS DMA ----
    size_t pb = (size_t)(b*D4 + z + kz) * (D4*D4*128);
    #pragma unroll
    for (int it = 0; it < 12; ++it) {
      __builtin_amdgcn_global_load_lds(
        (const __attribute__((address_space(1))) void*)(x4b + pb + srcoff[it]),
        (__attribute__((address_space(3))) void*)(lbase + it*4096 + wid*1024),
        16, 0, 0);
    }
    short8 A0[4], W0[4], A1[4], W1[4];
    c5_ldW(wB, kz*18 + 0, lane, W0);      // W prefetch overlaps DMA drain
    __syncthreads();                       // drains vmcnt (DMA) + joins block

    c5_ldA(sbuf, wid*63, 0, 0, l16, va, A0);   // s=0: ky=0,kx=0,kk=0
    #pragma unroll 1
    for (int ss = 0; ss < 18; ss += 2) {
      {
        int sn = ss + 1;
        int ky = sn/6, m6 = sn - ky*6, kx = m6 >> 1, kk = m6 & 1;
        c5_ldA(sbuf, (wid+ky)*63, kx, kk*4, l16, va, A1);
        c5_ldW(wB, kz*18 + sn, lane, W1);
      }
      c5_step(A0, W0, acc);
      if (ss + 2 < 18) {
        int sn = ss + 2;
        int ky = sn/6, m6 = sn - ky*6, kx = m6 >> 1, kk = m6 & 1;
        c5_ldA(sbuf, (wid+ky)*63, kx, kk*4, l16, va, A0);
        c5_ldW(wB, kz*18 + sn, lane, W0);
      } else if (kz < 2) {
        c5_ldW(wB, (kz+1)*18, lane, W0);   // preload next phase's first W
      }
      c5_step(A1, W1, acc);
    }
    __syncthreads();                       // protect buffer before next stage
  }

  // ---- epilogue: D row = co = cb*16+l16*4+r, col = x = a*16+ll ----
  const int yout = y0 + wid;
  if (yout < D5) {
    #pragma unroll
    for (int a = 0; a < 4; a++) {
      int x = va[a];
      if (x >= D5) continue;
      size_t sp = (size_t)(z*D5 + yout)*D5 + x;
      #pragma unroll
      for (int cb = 0; cb < 4; cb++)
        #pragma unroll
        for (int r = 0; r < 4; r++) {
          int co = cb*16 + l16*4 + r;
          float o = fmaxf((acc[a][cb][r] + bias[co])*s[co] + h[co], 0.f);
          out[(size_t)(b*64 + co)*D5CUBE + sp] = o;
        }
    }
  }
}

// ---------------- launcher ----------------
extern "C" void kernel_launch(void* const* d_in, const int* in_sizes, int n_in,
                              void* d_out, int out_size, void* d_ws, size_t ws_size,
                              hipStream_t stream) {
  const float* feat  = (const float*)d_in[0];
  const int*   coors = (const int*)d_in[1];
  const float* w1 = (const float*)d_in[3];
  const float* b1 = (const float*)d_in[4];
  const float* w2 = (const float*)d_in[5];
  const float* b2 = (const float*)d_in[6];
  const float* w3 = (const float*)d_in[7];
  const float* b3 = (const float*)d_in[8];
  const float* wt = (const float*)d_in[9];
  const float* bt = (const float*)d_in[10];
  const float* w5 = (const float*)d_in[11];
  const float* b5 = (const float*)d_in[12];
  const float* s1 = (const float*)d_in[13];
  const float* h1 = (const float*)d_in[14];
  const float* s2 = (const float*)d_in[15];
  const float* h2 = (const float*)d_in[16];
  const float* s3 = (const float*)d_in[17];
  const float* h3 = (const float*)d_in[18];
  const float* s4 = (const float*)d_in[19];
  const float* h4 = (const float*)d_in[20];
  const float* s5 = (const float*)d_in[21];
  const float* h5 = (const float*)d_in[22];
  int n = in_sizes[0] / 3;

  char* wsb = (char*)d_ws;
  float*          X0  = (float*)(wsb + OB_X0);
  float*          M0  = (float*)(wsb + OB_M0);
  float*          M1P = (float*)(wsb + OB_M1P);
  unsigned short* X1  = (unsigned short*)(wsb + OB_X1);
  unsigned short* X2  = (unsigned short*)(wsb + OB_X2);
  unsigned short* X3  = (unsigned short*)(wsb + OB_X3);
  float*          MT  = (float*)(wsb + OB_MT);
  unsigned short* X4  = (unsigned short*)(wsb + OB_X4);
  unsigned short* WB2 = (unsigned short*)(wsb + OB_WB2);
  unsigned short* WB3 = (unsigned short*)(wsb + OB_WB3);
  unsigned short* WBT = (unsigned short*)(wsb + OB_WBT);
  unsigned short* WB5 = (unsigned short*)(wsb + OB_WB5);

  hipMemsetAsync(wsb, 0, OB_MT, stream);

  k_repack<<<432, 256, 0, stream>>>(w2, WB2);
  k_repack<<<432, 256, 0, stream>>>(w3, WB3);
  k_repack<<<432, 256, 0, stream>>>(wt, WBT);
  k_repack<<<432, 256, 0, stream>>>(w5, WB5);

  k_scatter<<<(n+255)/256, 256, 0, stream>>>(feat, coors, n, X0, M0);

  {
    long long threads = (long long)NV1*C;
    k_conv1<<<(int)((threads+255)/256), 256, 0, stream>>>(X0, M0, X1, M1P, w1, b1, s1, h1);
  }

  constexpr int WAVES23 = (NV1 + 31) / 32;
  constexpr int BLK23   = (WAVES23 + 3) / 4;
  k_conv_mfma<2, D1, DP><<<BLK23, 256, 0, stream>>>(X1, WB2, X2, M1P, b2, s2, h2);
  k_conv_mfma<2, D1, DP><<<BLK23, 256, 0, stream>>>(X2, WB3, X3, M1P, b3, s3, h3);

  k_maskT<<<(NV4 + 255)/256, 256, 0, stream>>>(M1P, MT);

  constexpr int ROWS_T = BB*D4*D4;                // 7938
  k_convT_mfma<<<(ROWS_T + 3)/4, 256, 0, stream>>>(X3, WBT, X4, MT, bt, s4, h4);

  constexpr int BLK5 = BB * D5 * 16;              // 1952 blocks (b,z,ytile)
  k_conv5_mfma<<<BLK5, 256, 0, stream>>>(X4, WB5, (float*)d_out, b5, s5, h5);
}

// Round 6
// 372.232 us; speedup vs baseline: 26.6343x; 1.0135x over previous
//
#include <hip/hip_runtime.h>
#include <cstdint>

// ---------------- geometry ----------------
constexpr int BB = 2, C = 64;
constexpr int D1 = 31;          // conv1 out / conv2,3 spatial
constexpr int DP = 33;          // padded spatial for x1..x3
constexpr int D4 = 63;          // conv_transpose out spatial
constexpr int D5 = 61;          // conv5 out spatial
constexpr int D5CUBE = D5*D5*D5;   // 226981

constexpr int NV1 = BB*D1*D1*D1;   // 59582
constexpr int NVP = BB*DP*DP*DP;   // 71874
constexpr int NV4 = BB*D4*D4*D4;   // 500094
constexpr int NV5 = BB*D5*D5*D5;   // 453962

// ---------------- workspace layout (byte offsets) ----------------
constexpr size_t alup(size_t x) { return (x + 255) & ~(size_t)255; }
constexpr size_t OB_X0  = 0;                                     // [NVP][3] f32
constexpr size_t OB_M0  = alup(OB_X0  + (size_t)NVP*3*4);        // [NVP] f32
constexpr size_t OB_M1P = alup(OB_M0  + (size_t)NVP*4);          // [NVP] f32 padded mask
constexpr size_t OB_X1  = alup(OB_M1P + (size_t)NVP*4);          // [NVP][64] bf16 padded
constexpr size_t OB_X2  = alup(OB_X1  + (size_t)NVP*64*2);       // [NVP][64] bf16 padded
constexpr size_t OB_X3  = alup(OB_X2  + (size_t)NVP*64*2);       // [NVP][64] bf16 padded
constexpr size_t OB_MT  = alup(OB_X3  + (size_t)NVP*64*2);       // [NV4] f32 (fully rewritten)
constexpr size_t OB_X4  = alup(OB_MT  + (size_t)NV4*4);          // [NV4][64] bf16 (fully rewritten)
constexpr size_t OB_WB2 = alup(OB_X4  + (size_t)NV4*64*2);
constexpr size_t OB_WB3 = alup(OB_WB2 + (size_t)27*64*64*2);
constexpr size_t OB_WBT = alup(OB_WB3 + (size_t)27*64*64*2);
constexpr size_t OB_WB5 = alup(OB_WBT + (size_t)27*64*64*2);

// ---------------- types / helpers ----------------
typedef __attribute__((ext_vector_type(8))) short short8;
typedef __attribute__((ext_vector_type(4))) float f32x4;

__device__ inline unsigned short f2bf(float f) {
  unsigned int u = __float_as_uint(f);
  u = (u + 0x7FFFu + ((u >> 16) & 1u)) >> 16;   // RNE
  return (unsigned short)u;
}

template<int DD>
__device__ inline void decodev(int vox, int& b, int& z, int& y, int& x) {
  x = vox % DD; int r = vox / DD;
  y = r % DD;   r /= DD;
  z = r % DD;   b = r / DD;
}

// bijective XCD-chunked block swizzle (m204): each XCD gets a contiguous chunk
__device__ inline int xcd_swz(int bid, int nb) {
  int q = nb >> 3, r = nb & 7;
  int xcd = bid & 7, idx = bid >> 3;
  return (xcd < r ? xcd*(q+1) : r*(q+1) + (xcd - r)*q) + idx;
}

// ---------------- scatter ----------------
__global__ void k_scatter(const float* __restrict__ feat, const int* __restrict__ coors,
                          int n, float* __restrict__ x0, float* __restrict__ m0) {
  int i = blockIdx.x*blockDim.x + threadIdx.x;
  if (i >= n) return;
  int b = coors[4*i+0], z = coors[4*i+1], y = coors[4*i+2], x = coors[4*i+3];
  int v = ((b*DP + z)*DP + y)*DP + x;
  x0[v*3+0] = feat[3*i+0];
  x0[v*3+1] = feat[3*i+1];
  x0[v*3+2] = feat[3*i+2];
  m0[v] = 1.0f;
}

// ---------------- conv1: 3 -> 64, VALID, mask+act, bf16 out ----------------
__global__ void __launch_bounds__(256)
k_conv1(const float* __restrict__ x0, const float* __restrict__ m0,
        unsigned short* __restrict__ x1, float* __restrict__ m1p,
        const float* __restrict__ w1, const float* __restrict__ b1,
        const float* __restrict__ s1, const float* __restrict__ h1) {
  long long t = (long long)blockIdx.x*blockDim.x + threadIdx.x;
  if (t >= (long long)NV1*C) return;
  int co  = (int)(t & 63);
  int vox = (int)(t >> 6);
  int b, z, y, x; decodev<D1>(vox, b, z, y, x);
  float sum = 0.f, mm = 0.f;
  #pragma unroll
  for (int kz=0; kz<3; kz++)
  #pragma unroll
  for (int ky=0; ky<3; ky++)
  #pragma unroll
  for (int kx=0; kx<3; kx++) {
    int iv = ((b*DP + z+kz)*DP + y+ky)*DP + (x+kx);
    mm += m0[iv];
    const float* px = x0 + iv*3;
    const float* pw = w1 + ((kz*3+ky)*3+kx)*3*64 + co;
    sum += px[0]*pw[0] + px[1]*pw[64] + px[2]*pw[128];
  }
  bool m = mm > 0.f;
  float o = m ? fmaxf((sum + b1[co])*s1[co] + h1[co], 0.f) : 0.f;
  size_t pOff = (size_t)(((b*DP + z+1)*DP + y+1)*DP + (x+1));
  x1[pOff*C + co] = f2bf(o);
  if (co == 0) m1p[pOff] = m ? 1.f : 0.f;
}

// ---------------- fused weight repack (4 arrays) into MFMA fragment lane order ----------------
// dst[((t*2+kk)*4+cb)*512 + l*8 + j] = bf16(w[t][k][co]),
//   k = kk*32 + (l>>4)*8 + j, co = cb*16 + (l&15)
__global__ void k_repack4(const float* __restrict__ wa, const float* __restrict__ wb,
                          const float* __restrict__ wc, const float* __restrict__ wd,
                          unsigned short* __restrict__ da, unsigned short* __restrict__ db,
                          unsigned short* __restrict__ dc, unsigned short* __restrict__ dd) {
  int which = blockIdx.x / 432;                 // 110592/256 = 432 blocks per array
  int i = (blockIdx.x - which*432)*256 + threadIdx.x;
  const float* w = which == 0 ? wa : which == 1 ? wb : which == 2 ? wc : wd;
  unsigned short* dst = which == 0 ? da : which == 1 ? db : which == 2 ? dc : dd;
  int co = i & 63, k = (i >> 6) & 63, t = i >> 12;
  int kk = k >> 5, q = (k >> 3) & 3, j = k & 7, cb = co >> 4, l = q*16 + (co & 15);
  dst[(size_t)((t*2+kk)*4+cb)*512 + l*8 + j] = f2bf(w[i]);
}

// ---------------- MFMA implicit-GEMM conv (3^3, 64->64), padded bf16 out + mask/act ----------------
template<int NA, int DOUT, int DIN>
__global__ void __launch_bounds__(256)
k_conv_mfma(const unsigned short* __restrict__ inBF, const unsigned short* __restrict__ wB,
            unsigned short* __restrict__ outPtr, const float* __restrict__ m1p,
            const float* __restrict__ bias, const float* __restrict__ s,
            const float* __restrict__ h) {
  constexpr int NVOX = BB*DOUT*DOUT*DOUT;
  const int lane = threadIdx.x & 63;
  const int wid  = threadIdx.x >> 6;
  const int wave = xcd_swz(blockIdx.x, gridDim.x)*4 + wid;
  const int vb   = wave * (NA*16);

  int rowb[NA];
  #pragma unroll
  for (int a = 0; a < NA; a++) {
    int vox = vb + a*16 + (lane & 15);
    vox = vox < NVOX ? vox : NVOX-1;
    int b, z, y, x; decodev<DOUT>(vox, b, z, y, x);
    rowb[a] = (((b*DIN + z)*DIN + y)*DIN + x)*64;
  }
  const int koff = (lane >> 4) * 8;

  f32x4 acc[NA][4];
  #pragma unroll
  for (int a = 0; a < NA; a++)
    #pragma unroll
    for (int cb = 0; cb < 4; cb++)
      acc[a][cb] = f32x4{0.f, 0.f, 0.f, 0.f};

  #pragma unroll 1
  for (int t = 0; t < 27; ++t) {
    int kz = t / 9, rr = t - kz*9;
    int ky = rr / 3, kx = rr - ky*3;
    const int toff = ((kz*DIN + ky)*DIN + kx)*64;
    #pragma unroll
    for (int kk = 0; kk < 2; ++kk) {
      short8 A[NA];
      #pragma unroll
      for (int a = 0; a < NA; a++)
        A[a] = *reinterpret_cast<const short8*>(inBF + rowb[a] + toff + kk*32 + koff);
      short8 Bv[4];
      const unsigned short* wp = wB + (size_t)(t*2+kk)*2048 + lane*8;
      #pragma unroll
      for (int cb = 0; cb < 4; cb++)
        Bv[cb] = *reinterpret_cast<const short8*>(wp + cb*512);
      #pragma unroll
      for (int a = 0; a < NA; a++)
        #pragma unroll
        for (int cb = 0; cb < 4; cb++)
          acc[a][cb] = __builtin_amdgcn_mfma_f32_16x16x32_bf16(A[a], Bv[cb], acc[a][cb], 0, 0, 0);
    }
  }

  float bv[4], sv[4], hv[4];
  #pragma unroll
  for (int cb = 0; cb < 4; cb++) {
    int c = cb*16 + (lane & 15);
    bv[cb] = bias[c]; sv[cb] = s[c]; hv[cb] = h[c];
  }

  #pragma unroll
  for (int a = 0; a < NA; a++)
    #pragma unroll
    for (int r = 0; r < 4; r++) {
      int vox = vb + a*16 + (lane >> 4)*4 + r;
      if (vox >= NVOX) continue;
      int b, z, y, x; decodev<DOUT>(vox, b, z, y, x);
      size_t pOff = (size_t)(((b*DP + z+1)*DP + y+1)*DP + (x+1));
      bool m = m1p[pOff] > 0.f;
      #pragma unroll
      for (int cb = 0; cb < 4; cb++) {
        float o = m ? fmaxf((acc[a][cb][r] + bv[cb])*sv[cb] + hv[cb], 0.f) : 0.f;
        outPtr[pOff*64 + cb*16 + (lane & 15)] = f2bf(o);
      }
    }
}

// ---------------- mT mask precompute ----------------
__global__ void __launch_bounds__(256)
k_maskT(const float* __restrict__ m1p, float* __restrict__ mt) {
  int vox = blockIdx.x*256 + threadIdx.x;
  if (vox >= NV4) return;
  int b, zo, yo, xo; decodev<D4>(vox, b, zo, yo, xo);
  float mm = 0.f;
  for (int kz = 0; kz < 3; kz++) {
    if ((zo + kz) & 1) continue;
    int izp = ((zo + kz - 2) >> 1) + 1;
    for (int ky = 0; ky < 3; ky++) {
      if ((yo + ky) & 1) continue;
      int iyp = ((yo + ky - 2) >> 1) + 1;
      for (int kx = 0; kx < 3; kx++) {
        if ((xo + kx) & 1) continue;
        int ixp = ((xo + kx - 2) >> 1) + 1;
        mm += m1p[((b*DP + izp)*DP + iyp)*DP + ixp];
      }
    }
  }
  mt[vox] = mm;
}

// ---------------- conv_transpose stride2 VALID via MFMA (parity decomposition) ----------------
__global__ void __launch_bounds__(256)
k_convT_mfma(const unsigned short* __restrict__ x3, const unsigned short* __restrict__ wB,
             unsigned short* __restrict__ x4, const float* __restrict__ mt,
             const float* __restrict__ bias, const float* __restrict__ s,
             const float* __restrict__ h) {
  const int lane = threadIdx.x & 63;
  const int wid  = threadIdx.x >> 6;
  const int w    = xcd_swz(blockIdx.x, gridDim.x)*4 + wid;
  if (w >= BB*D4*D4) return;
  const int b  = w / (D4*D4);
  const int rm = w % (D4*D4);
  const int zo = rm / D4;
  const int yo = rm % D4;
  const int ii = lane & 15;
  const int koff = (lane >> 4) * 8;

  f32x4 acc[4][4];
  #pragma unroll
  for (int a = 0; a < 4; a++)
    #pragma unroll
    for (int cb = 0; cb < 4; cb++)
      acc[a][cb] = f32x4{0.f, 0.f, 0.f, 0.f};

  #pragma unroll 1
  for (int kz = 0; kz < 3; kz++) {
    if ((zo + kz) & 1) continue;
    const int izp = ((zo + kz - 2) >> 1) + 1;
    #pragma unroll 1
    for (int ky = 0; ky < 3; ky++) {
      if ((yo + ky) & 1) continue;
      const int iyp = ((yo + ky - 2) >> 1) + 1;
      const size_t planeBase = ((size_t)((b*DP + izp)*DP + iyp))*DP*64;
      #pragma unroll
      for (int kx = 0; kx < 3; kx++) {
        const int apar  = kx & 1;
        const int xoffE = ((kx + apar - 2) >> 1) + 1;
        const int t = (kz*3 + ky)*3 + kx;
        #pragma unroll
        for (int kk = 0; kk < 2; ++kk) {
          short8 Bv[4];
          const unsigned short* wpk = wB + (size_t)(t*2+kk)*2048 + lane*8;
          #pragma unroll
          for (int cb = 0; cb < 4; cb++)
            Bv[cb] = *reinterpret_cast<const short8*>(wpk + cb*512);
          #pragma unroll
          for (int ablk = 0; ablk < 2; ablk++) {
            const int ixp = ablk*16 + ii + xoffE;
            short8 A = *reinterpret_cast<const short8*>(x3 + planeBase + (size_t)ixp*64 + kk*32 + koff);
            const int afr = apar*2 + ablk;
            #pragma unroll
            for (int cb = 0; cb < 4; cb++)
              acc[afr][cb] = __builtin_amdgcn_mfma_f32_16x16x32_bf16(A, Bv[cb], acc[afr][cb], 0, 0, 0);
          }
        }
      }
    }
  }

  float bv[4], sv[4], hv[4];
  #pragma unroll
  for (int cb = 0; cb < 4; cb++) {
    int c = cb*16 + (lane & 15);
    bv[cb] = bias[c]; sv[cb] = s[c]; hv[cb] = h[c];
  }
  const int rowBase = ((b*D4 + zo)*D4 + yo)*D4;
  #pragma unroll
  for (int a = 0; a < 4; a++) {
    const int ablk = a & 1, apar = a >> 1;
    #pragma unroll
    for (int r = 0; r < 4; r++) {
      const int row = (lane >> 4)*4 + r;
      const int xo  = 2*(ablk*16 + row) + apar;
      if (xo >= D4) continue;
      const int vox = rowBase + xo;
      const bool m = mt[vox] > 0.f;
      #pragma unroll
      for (int cb = 0; cb < 4; cb++) {
        float o = m ? fmaxf((acc[a][cb][r] + bv[cb])*sv[cb] + hv[cb], 0.f) : 0.f;
        x4[(size_t)vox*64 + cb*16 + (lane & 15)] = f2bf(o);
      }
    }
  }
}

// ---------------- conv5 v4: (kz,ky)-phase pipeline, double-buffered 32KB halves ----------------
// Block = 4 waves = out rows (b, z, y0..y0+3), 61 x, 64 co.
// Phase p = (kz=p/3, ky=p%3): compute 6 steps (kx,kk) from half p&1 while DMA-staging
// phase p+1's 4 rows (64 vox-padded x 128B) into the other half. W slots sweep 0..53
// sequentially (slot = p*6 + kx*2 + kk) with a depth-1 register chain across phases.
// LDS chunk swizzle: logical chunk c16 stored at phys c16 ^ (v&7); DMA dest linear,
// source pre-swizzled; ds_read applies same XOR (rule #21).
__device__ __forceinline__ void c5_step(const short8 (&A)[4], const short8 (&W)[4],
                                        f32x4 (&acc)[4][4]) {
  #pragma unroll
  for (int a = 0; a < 4; a++)
    #pragma unroll
    for (int cb = 0; cb < 4; cb++)
      acc[a][cb] = __builtin_amdgcn_mfma_f32_16x16x32_bf16(W[cb], A[a], acc[a][cb], 0, 0, 0);
}

__global__ void __launch_bounds__(256, 2)
k_conv5_mfma(const unsigned short* __restrict__ x4, const unsigned short* __restrict__ wB,
             float* __restrict__ out, const float* __restrict__ bias,
             const float* __restrict__ s, const float* __restrict__ h) {
  __shared__ short8 sbuf[2][2048];          // 2 x 32KB halves
  const int tid  = threadIdx.x;
  const int lane = tid & 63;
  const int wid  = tid >> 6;                // out-row j within tile
  const int ll   = lane & 15;
  const int l16  = lane >> 4;

  const int blk   = xcd_swz(blockIdx.x, gridDim.x);
  const int ytile = blk & 15;               // 16 y-tiles
  const int rzb   = blk >> 4;
  const int z     = rzb % D5;
  const int b     = rzb / D5;
  const int y0    = ytile * 4;

  // per-it stage geometry (phase-independent): logical chunk g -> (row r, voxel v, swz c16)
  int st_r[8], st_base[8];
  #pragma unroll
  for (int it = 0; it < 8; ++it) {
    int g = it*256 + tid; g = g > 2015 ? 2015 : g;   // 2016 = 4 rows * 63 vox * 8 chunks
    int r = g / 504, rem = g - r*504;
    int v = rem >> 3, c16p = rem & 7;
    int c16l = c16p ^ (v & 7);                        // logical chunk stored at phys c16p
    st_r[it] = r;
    st_base[it] = (v << 7) + (c16l << 4);
  }

  const char* x4b = (const char*)x4;

  f32x4 acc[4][4];
  #pragma unroll
  for (int a = 0; a < 4; a++)
    #pragma unroll
    for (int cb = 0; cb < 4; cb++)
      acc[a][cb] = f32x4{0.f, 0.f, 0.f, 0.f};

  // ---- stage helper (issues 8 global->LDS DMAs per wave) ----
  auto STAGE = [&](int kzn, int kyn, int hn) {
    size_t pb = (size_t)(b*D4 + z + kzn) * (D4*D4*128);
    char* dst = (char*)&sbuf[hn][0];
    #pragma unroll
    for (int it = 0; it < 8; ++it) {
      int yin = y0 + st_r[it] + kyn; yin = yin > 62 ? 62 : yin;
      __builtin_amdgcn_global_load_lds(
        (const __attribute__((address_space(1))) void*)(x4b + pb + (size_t)yin*8064 + st_base[it]),
        (__attribute__((address_space(3))) void*)(dst + it*4096 + wid*1024),
        16, 0, 0);
    }
  };
  auto LDA = [&](int hh, int kx, int kk, short8 (&A)[4]) {
    #pragma unroll
    for (int a = 0; a < 4; a++) {
      int v  = a*16 + ll + kx;
      int ch = wid*504 + v*8 + ((kk*4 + l16) ^ (v & 7));
      A[a] = sbuf[hh][ch];
    }
  };
  auto LDW = [&](int slot, short8 (&W)[4]) {
    const unsigned short* wp = wB + (size_t)slot*2048 + lane*8;
    #pragma unroll
    for (int cb = 0; cb < 4; cb++)
      W[cb] = *reinterpret_cast<const short8*>(wp + cb*512);
  };

  short8 A0[4], A1[4], W0[4], W1[4];

  // prologue: stage phase 0 (kz=0,ky=0) into half 0; preload W slot 0
  STAGE(0, 0, 0);
  LDW(0, W0);
  __syncthreads();

  int kzn = 0, kyn = 1;                      // geometry of phase p+1
  #pragma unroll 1
  for (int p = 0; p < 9; ++p) {
    const int hh = p & 1;
    if (p < 8) {
      STAGE(kzn, kyn, hh ^ 1);
      kyn++; if (kyn == 3) { kyn = 0; kzn++; }
    }
    LDA(hh, 0, 0, A0);
    const int sbase = p*6;
    #pragma unroll
    for (int st = 0; st < 6; ++st) {
      const int kxn = (st+1) >> 1, kkn = (st+1) & 1;
      if (st < 5) {
        if (st & 1) LDA(hh, kxn, kkn, A0); else LDA(hh, kxn, kkn, A1);
      }
      if (sbase + st + 1 < 54) {
        if (st & 1) LDW(sbase + st + 1, W0); else LDW(sbase + st + 1, W1);
      }
      if (st & 1) c5_step(A1, W1, acc); else c5_step(A0, W0, acc);
    }
    __syncthreads();
  }

  // ---- epilogue: D row = co = cb*16+l16*4+r, col = x = a*16+ll ----
  const int yout = y0 + wid;
  if (yout < D5) {
    #pragma unroll
    for (int a = 0; a < 4; a++) {
      int x = a*16 + ll;
      if (x >= D5) continue;
      size_t sp = (size_t)(z*D5 + yout)*D5 + x;
      #pragma unroll
      for (int cb = 0; cb < 4; cb++)
        #pragma unroll
        for (int r = 0; r < 4; r++) {
          int co = cb*16 + l16*4 + r;
          float o = fmaxf((acc[a][cb][r] + bias[co])*s[co] + h[co], 0.f);
          out[(size_t)(b*64 + co)*D5CUBE + sp] = o;
        }
    }
  }
}

// ---------------- launcher ----------------
extern "C" void kernel_launch(void* const* d_in, const int* in_sizes, int n_in,
                              void* d_out, int out_size, void* d_ws, size_t ws_size,
                              hipStream_t stream) {
  const float* feat  = (const float*)d_in[0];
  const int*   coors = (const int*)d_in[1];
  const float* w1 = (const float*)d_in[3];
  const float* b1 = (const float*)d_in[4];
  const float* w2 = (const float*)d_in[5];
  const float* b2 = (const float*)d_in[6];
  const float* w3 = (const float*)d_in[7];
  const float* b3 = (const float*)d_in[8];
  const float* wt = (const float*)d_in[9];
  const float* bt = (const float*)d_in[10];
  const float* w5 = (const float*)d_in[11];
  const float* b5 = (const float*)d_in[12];
  const float* s1 = (const float*)d_in[13];
  const float* h1 = (const float*)d_in[14];
  const float* s2 = (const float*)d_in[15];
  const float* h2 = (const float*)d_in[16];
  const float* s3 = (const float*)d_in[17];
  const float* h3 = (const float*)d_in[18];
  const float* s4 = (const float*)d_in[19];
  const float* h4 = (const float*)d_in[20];
  const float* s5 = (const float*)d_in[21];
  const float* h5 = (const float*)d_in[22];
  int n = in_sizes[0] / 3;

  char* wsb = (char*)d_ws;
  float*          X0  = (float*)(wsb + OB_X0);
  float*          M0  = (float*)(wsb + OB_M0);
  float*          M1P = (float*)(wsb + OB_M1P);
  unsigned short* X1  = (unsigned short*)(wsb + OB_X1);
  unsigned short* X2  = (unsigned short*)(wsb + OB_X2);
  unsigned short* X3  = (unsigned short*)(wsb + OB_X3);
  float*          MT  = (float*)(wsb + OB_MT);
  unsigned short* X4  = (unsigned short*)(wsb + OB_X4);
  unsigned short* WB2 = (unsigned short*)(wsb + OB_WB2);
  unsigned short* WB3 = (unsigned short*)(wsb + OB_WB3);
  unsigned short* WBT = (unsigned short*)(wsb + OB_WBT);
  unsigned short* WB5 = (unsigned short*)(wsb + OB_WB5);

  hipMemsetAsync(wsb, 0, OB_MT, stream);

  k_repack4<<<1728, 256, 0, stream>>>(w2, w3, wt, w5, WB2, WB3, WBT, WB5);

  k_scatter<<<(n+255)/256, 256, 0, stream>>>(feat, coors, n, X0, M0);

  {
    long long threads = (long long)NV1*C;
    k_conv1<<<(int)((threads+255)/256), 256, 0, stream>>>(X0, M0, X1, M1P, w1, b1, s1, h1);
  }

  constexpr int WAVES23 = (NV1 + 31) / 32;
  constexpr int BLK23   = (WAVES23 + 3) / 4;
  k_conv_mfma<2, D1, DP><<<BLK23, 256, 0, stream>>>(X1, WB2, X2, M1P, b2, s2, h2);
  k_conv_mfma<2, D1, DP><<<BLK23, 256, 0, stream>>>(X2, WB3, X3, M1P, b3, s3, h3);

  k_maskT<<<(NV4 + 255)/256, 256, 0, stream>>>(M1P, MT);

  constexpr int ROWS_T = BB*D4*D4;                // 7938
  k_convT_mfma<<<(ROWS_T + 3)/4, 256, 0, stream>>>(X3, WBT, X4, MT, bt, s4, h4);

  constexpr int BLK5 = BB * D5 * 16;              // 1952 blocks (b,z,ytile)
  k_conv5_mfma<<<BLK5, 256, 0, stream>>>(X4, WB5, (float*)d_out, b5, s5, h5);
}